// Round 7
// baseline (117.524 us; speedup 1.0000x reference)
//
#include <hip/hip_runtime.h>
#include <hip/hip_bf16.h>
#include <stdint.h>

using f32x4 = __attribute__((ext_vector_type(4))) float;
using s16x8 = __attribute__((ext_vector_type(8))) short;
using s16x4 = __attribute__((ext_vector_type(4))) short;

__device__ __forceinline__ unsigned short f2bf(float f) {
  union { float f; unsigned int u; } v; v.f = f;
  return (unsigned short)((v.u + 0x7FFFu + ((v.u >> 16) & 1u)) >> 16);
}

__device__ __forceinline__ float exp2_(float x) {
  float r;
  asm("v_exp_f32 %0, %1" : "=v"(r) : "v"(x));
  return r;
}

// pack 4 f32 -> 4 bf16 via 2x v_cvt_pk_bf16_f32
__device__ __forceinline__ s16x4 pk4(float a, float b, float c, float d) {
  union { unsigned u[2]; s16x4 v; } r;
  asm("v_cvt_pk_bf16_f32 %0, %1, %2" : "=v"(r.u[0]) : "v"(a), "v"(b));
  asm("v_cvt_pk_bf16_f32 %0, %1, %2" : "=v"(r.u[1]) : "v"(c), "v"(d));
  return r.v;
}

__device__ __forceinline__ short pbf(float f) {
  __hip_bfloat16 h = __float2bfloat16(f);
  return *(short*)&h;
}

#define GLD16(gp, lp) __builtin_amdgcn_global_load_lds( \
    (const __attribute__((address_space(1))) unsigned int*)(uintptr_t)(gp), \
    (__attribute__((address_space(3))) unsigned int*)(uintptr_t)(lp), 16, 0, 0)

__device__ __forceinline__ f32x4 mfma32(s16x8 a, s16x8 b, f32x4 c) {
  return __builtin_amdgcn_mfma_f32_16x16x32_bf16(a, b, c, 0, 0, 0);
}

#if __has_builtin(__builtin_amdgcn_mfma_f32_16x16x16bf16_1k)
__device__ __forceinline__ f32x4 mfma16(s16x4 a, s16x4 b, f32x4 c) {
  return __builtin_amdgcn_mfma_f32_16x16x16bf16_1k(a, b, c, 0, 0, 0);
}
#else
__device__ __forceinline__ f32x4 mfma16(s16x4 a, s16x4 b, f32x4 c) {
  f32x4 d;
  asm volatile("v_mfma_f32_16x16x16_bf16 %0, %1, %2, %3"
               : "=v"(d) : "v"(a), "v"(b), "v"(c));
  return d;
}
#endif

// ---------------- prep: fused x-convert + 4 weight transposes ----------------
__global__ __launch_bounds__(256)
void prep(const float* __restrict__ x,
          const float* __restrict__ Wq, const float* __restrict__ Wk,
          const float* __restrict__ Wv, const float* __restrict__ Wo,
          unsigned short* __restrict__ xb, unsigned short* __restrict__ Wt) {
  __shared__ float tile[64][65];
  int blk = blockIdx.x;
  int tid = threadIdx.x;
  if (blk < 1024) {
    const float4* xi = (const float4*)x;
    ushort4* xo = (ushort4*)xb;
    #pragma unroll
    for (int j = 0; j < 4; ++j) {
      int i = blk * 1024 + j * 256 + tid;
      float4 v = xi[i];
      ushort4 o;
      o.x = f2bf(v.x); o.y = f2bf(v.y); o.z = f2bf(v.z); o.w = f2bf(v.w);
      xo[i] = o;
    }
  } else {
    int wid = blk - 1024;
    int which = wid >> 8, t = wid & 255;
    const float* W = (which == 0) ? Wq : (which == 1) ? Wk : (which == 2) ? Wv : Wo;
    unsigned short* dst = Wt + (size_t)which * 1048576;
    int k0 = (t & 15) * 64, n0 = (t >> 4) * 64;
    int tx = tid & 63, ty = tid >> 6;
    #pragma unroll
    for (int j = 0; j < 64; j += 4)
      tile[ty + j][tx] = W[(size_t)(k0 + ty + j) * 1024 + n0 + tx];
    __syncthreads();
    #pragma unroll
    for (int j = 0; j < 64; j += 4)
      dst[(size_t)(n0 + ty + j) * 1024 + k0 + tx] = f2bf(tile[tx][ty + j]);
  }
}

// ---------------- fused QKV GEMM: [4096,1024] x [1024,3072] ----------------
// Epilogue writes q:[B,H,S,Dh] (pre-scaled by log2e/8), K in MFMA fragment
// order, and V in PAIRED fragment order (kv-16-tile pairs adjacent so attn
// reads V as b128):
//   vfrag2[pair][Tp=kv>>5][dt=dh>>4][lane=g*16+c][par=(kv>>4)&1][e=kv&3]
__global__ __launch_bounds__(256)
void qkv_gemm(const unsigned short* __restrict__ A,
              const unsigned short* __restrict__ Bt,
              const float* __restrict__ bq, const float* __restrict__ bk,
              const float* __restrict__ bv,
              unsigned short* __restrict__ qo, unsigned short* __restrict__ kf,
              unsigned short* __restrict__ vf) {
  __shared__ unsigned short ldsA[2][4096];
  __shared__ unsigned short ldsB[2][4096];
  int orig = blockIdx.x;                    // 768 wgs
  int wg = (orig & 7) * 96 + (orig >> 3);
  int bm = wg / 24;
  int bn = wg - bm * 24;
  int m0 = bm << 7, n0 = bn << 7;
  int tid = threadIdx.x;
  int w = tid >> 6, ln = tid & 63;
  int g = ln >> 4, c = ln & 15;
  int wr = w >> 1, wc = w & 1;

  const unsigned short* ga = A + (size_t)(m0 + (tid >> 2)) * 1024 + (tid & 3) * 8;
  const unsigned short* gb = Bt + (size_t)(n0 + (tid >> 2)) * 1024 + (tid & 3) * 8;
  int lb = w * 512;

  f32x4 acc[4][4];
  f32x4 zero = {0.f, 0.f, 0.f, 0.f};
  #pragma unroll
  for (int m = 0; m < 4; ++m)
    #pragma unroll
    for (int n = 0; n < 4; ++n) acc[m][n] = zero;

  GLD16(ga, &ldsA[0][lb]);
  GLD16(ga + 65536, &ldsA[0][2048 + lb]);
  GLD16(gb, &ldsB[0][lb]);
  GLD16(gb + 65536, &ldsB[0][2048 + lb]);
  __syncthreads();

  int aoff = (wr * 64 + c) * 32 + g * 8;
  int boff = (wc * 64 + c) * 32 + g * 8;

  int cur = 0;
  for (int t = 0; t < 32; ++t) {
    if (t < 31) {
      const unsigned short* ga2 = ga + (t + 1) * 32;
      const unsigned short* gb2 = gb + (t + 1) * 32;
      int nb = cur ^ 1;
      GLD16(ga2, &ldsA[nb][lb]);
      GLD16(ga2 + 65536, &ldsA[nb][2048 + lb]);
      GLD16(gb2, &ldsB[nb][lb]);
      GLD16(gb2 + 65536, &ldsB[nb][2048 + lb]);
    }
    s16x8 af[4], bf[4];
    #pragma unroll
    for (int m = 0; m < 4; ++m)
      af[m] = *(const s16x8*)&ldsA[cur][aoff + m * 512];
    #pragma unroll
    for (int n = 0; n < 4; ++n)
      bf[n] = *(const s16x8*)&ldsB[cur][boff + n * 512];
    #pragma unroll
    for (int m = 0; m < 4; ++m)
      #pragma unroll
      for (int n = 0; n < 4; ++n)
        acc[m][n] = mfma32(af[m], bf[n], acc[m][n]);
    __syncthreads();
    cur ^= 1;
  }

  #pragma unroll
  for (int n = 0; n < 4; ++n) {
    int cg = n0 + wc * 64 + n * 16 + c;     // 0..3071
    int p = cg >> 10;                       // 0=q 1=k 2=v
    int d = cg & 1023;
    int hh = d >> 6, dh = d & 63;
    const float* bp = (p == 0) ? bq : (p == 1) ? bk : bv;
    float bias = bp[d];
    #pragma unroll
    for (int m = 0; m < 4; ++m) {
      int r = m0 + wr * 64 + m * 16 + g * 4;  // rows r..r+3 (e=0..3)
      int b = r >> 11, s = r & 2047;
      size_t pv = (size_t)((b << 4) + hh);
      if (p == 2) {
        int T = s >> 4;                     // kv 16-tile; s&15 == g*4 + e
        int Tp = T >> 1, par = T & 1;
        int dtp = dh >> 4;                  // dh&15 == c
        ushort4 pk;
        pk.x = f2bf(acc[m][n][0] + bias);
        pk.y = f2bf(acc[m][n][1] + bias);
        pk.z = f2bf(acc[m][n][2] + bias);
        pk.w = f2bf(acc[m][n][3] + bias);
        *(ushort4*)&vf[pv * 131072 +
                       (size_t)(((Tp * 4 + dtp) * 64 + g * 16 + c) * 8 + par * 4)] = pk;
      } else if (p == 1) {
        int T = s >> 4;
        int h2 = dh >> 5, gp = (dh >> 3) & 3, j = dh & 7;
        unsigned short* kd = kf + pv * 131072 + T * 1024 + h2 * 512 +
                             (gp * 16 + (s & 15)) * 8 + j;
        kd[0]  = f2bf(acc[m][n][0] + bias);
        kd[8]  = f2bf(acc[m][n][1] + bias);
        kd[16] = f2bf(acc[m][n][2] + bias);
        kd[24] = f2bf(acc[m][n][3] + bias);
      } else {
        const float sc = 0.180336880111120f;  // 1/8 * log2(e)
        size_t base = (pv * 2048 + s) * 64 + dh;
        qo[base]       = f2bf((acc[m][n][0] + bias) * sc);
        qo[base + 64]  = f2bf((acc[m][n][1] + bias) * sc);
        qo[base + 128] = f2bf((acc[m][n][2] + bias) * sc);
        qo[base + 192] = f2bf((acc[m][n][3] + bias) * sc);
      }
    }
  }
}

// ---------------- flash attention (64 q-rows/wave, fixed-max softmax) --------
// 4 waves x 64 q-rows (4 j-tiles) = 256 rows/block; 256 wgs (1 block/CU).
// Halved wave count vs R6 -> half the aggregate LDS K/V read traffic; V read
// as b128 pairs. KVB=64 LDS-staged (dbuf 32KB), counted vmcnt(4). Fixed-max
// softmax (logits in log2 domain, |S| << 127 -> exp2 safe, softmax
// shift-invariant). Zero cross-lane ops in the loop.
__global__ __launch_bounds__(256, 1)
void attn_fwd(const unsigned short* __restrict__ q,
              const unsigned short* __restrict__ kfb,
              const unsigned short* __restrict__ vfb,
              unsigned short* __restrict__ ao) {
  __shared__ unsigned short ldsKV[2][8192];  // [K: 0..4095][V: 4096..8191]
  int orig = blockIdx.x;                    // 256 wgs
  int wg = (orig & 7) * 32 + (orig >> 3);   // XCD-contiguous
  int pair = wg >> 3, qt = wg & 7;          // 8 blocks (256 q-rows) per pair
  int tid = threadIdx.x;
  int w = tid >> 6, ln = tid & 63;
  int g = ln >> 4, c = ln & 15;
  int q0 = qt * 256 + w * 64;
  const unsigned short* qp = q + (size_t)pair * 131072;
  const char* kbase = (const char*)(kfb + (size_t)pair * 131072);
  const char* vbase = (const char*)(vfb + (size_t)pair * 131072);

  // staging: waves 0,1 -> K halves, waves 2,3 -> V halves; 4KB each
  const char* ssrc = ((w < 2) ? kbase : vbase) + (w & 1) * 4096;
  int dsto = (w >= 2 ? 8192 : 0) + (w & 1) * 4096;

  s16x8 qf[4][2];
  #pragma unroll
  for (int j = 0; j < 4; ++j)
    #pragma unroll
    for (int h = 0; h < 2; ++h)
      qf[j][h] = *(const s16x8*)&qp[(q0 + j * 16 + c) * 64 + h * 32 + g * 8];

  f32x4 acc[4][4];   // [j][dt]
  f32x4 zero = {0.f, 0.f, 0.f, 0.f};
  #pragma unroll
  for (int j = 0; j < 4; ++j)
    #pragma unroll
    for (int dt = 0; dt < 4; ++dt) acc[j][dt] = zero;
  float l[4] = {0.f, 0.f, 0.f, 0.f};

  // prologue: stage tile 0 into buf 0
  #pragma unroll
  for (int j = 0; j < 4; ++j)
    GLD16(ssrc + j * 1024 + ln * 16, (char*)&ldsKV[0][0] + dsto + j * 1024);

  int buf = 0;
  for (int kv0 = 0; kv0 < 2048; kv0 += 64) {
    if (kv0 + 64 < 2048) {
      const char* s2 = ssrc + (kv0 + 64) * 128;
      char* d2 = (char*)&ldsKV[buf ^ 1][0] + dsto;
      #pragma unroll
      for (int j = 0; j < 4; ++j)
        GLD16(s2 + j * 1024 + ln * 16, d2 + j * 1024);
      asm volatile("s_waitcnt vmcnt(4)" ::: "memory");
    } else {
      asm volatile("s_waitcnt vmcnt(0)" ::: "memory");
    }
    __builtin_amdgcn_s_barrier();

    const unsigned short* L = ldsKV[buf];
    // K fragments (stride-1 b128)
    s16x8 kc[4][2];
    #pragma unroll
    for (int kt = 0; kt < 4; ++kt) {
      kc[kt][0] = *(const s16x8*)&L[kt * 1024 + ln * 8];
      kc[kt][1] = *(const s16x8*)&L[kt * 1024 + 512 + ln * 8];
    }
    // V fragment pairs (stride-1 b128): vv2[dt][tp] = kv tiles 2tp,2tp+1
    s16x8 vv2[4][2];
    #pragma unroll
    for (int dt = 0; dt < 4; ++dt)
      #pragma unroll
      for (int tp = 0; tp < 2; ++tp)
        vv2[dt][tp] = *(const s16x8*)&L[4096 + tp * 2048 + dt * 512 + ln * 8];

    // QK^T + exp2 + pack, kt-pair at a time (bounds register liveness)
    s16x4 pa[4][4];    // [j][kt]
    #pragma unroll
    for (int ktp = 0; ktp < 2; ++ktp) {
      f32x4 st[2][4];  // [kt within pair][j]
      __builtin_amdgcn_s_setprio(1);
      #pragma unroll
      for (int k2 = 0; k2 < 2; ++k2) {
        int kt = ktp * 2 + k2;
        #pragma unroll
        for (int j = 0; j < 4; ++j) {
          f32x4 t = zero;
          t = mfma32(kc[kt][0], qf[j][0], t);
          t = mfma32(kc[kt][1], qf[j][1], t);
          st[k2][j] = t;
        }
      }
      __builtin_amdgcn_s_setprio(0);
      #pragma unroll
      for (int k2 = 0; k2 < 2; ++k2) {
        int kt = ktp * 2 + k2;
        #pragma unroll
        for (int j = 0; j < 4; ++j) {
          float p0 = exp2_(st[k2][j][0]), p1 = exp2_(st[k2][j][1]);
          float p2 = exp2_(st[k2][j][2]), p3 = exp2_(st[k2][j][3]);
          l[j] += (p0 + p1) + (p2 + p3);
          pa[j][kt] = pk4(p0, p1, p2, p3);
        }
      }
    }

    // PV: O += P * V  (V low half = even tile, high half = odd tile)
    __builtin_amdgcn_s_setprio(1);
    #pragma unroll
    for (int dt = 0; dt < 4; ++dt)
      #pragma unroll
      for (int tp = 0; tp < 2; ++tp) {
        s16x4 vlo = __builtin_shufflevector(vv2[dt][tp], vv2[dt][tp], 0, 1, 2, 3);
        s16x4 vhi = __builtin_shufflevector(vv2[dt][tp], vv2[dt][tp], 4, 5, 6, 7);
        #pragma unroll
        for (int j = 0; j < 4; ++j) {
          acc[j][dt] = mfma16(pa[j][tp * 2], vlo, acc[j][dt]);
          acc[j][dt] = mfma16(pa[j][tp * 2 + 1], vhi, acc[j][dt]);
        }
      }
    __builtin_amdgcn_s_setprio(0);

    __builtin_amdgcn_s_barrier();
    buf ^= 1;
  }

  // final l reduction across the 4 g-copies of each q-column
  int b = pair >> 4, hh = pair & 15;
  #pragma unroll
  for (int j = 0; j < 4; ++j) {
    float lj = l[j];
    lj += __shfl_xor(lj, 16);
    lj += __shfl_xor(lj, 32);
    float li = 1.f / lj;
    #pragma unroll
    for (int e = 0; e < 4; ++e) {
      float iv = __shfl(li, g * 4 + e);
      size_t r0 = ((size_t)(b * 2048 + q0 + j * 16 + g * 4 + e) * 16 + hh) * 64;
      #pragma unroll
      for (int dt = 0; dt < 4; ++dt)
        ao[r0 + dt * 16 + c] = (unsigned short)pbf(acc[j][dt][e] * iv);
    }
  }
}

// ---------------- output GEMM: ao[4096,1024] x Wo -> fp32 out ----------------
__global__ __launch_bounds__(256)
void out_gemm(const unsigned short* __restrict__ A,
              const unsigned short* __restrict__ Bt,
              const float* __restrict__ bo, float* __restrict__ out) {
  __shared__ unsigned short lds[2][6144];   // A @0..2047, B @2048..6143
  int orig = blockIdx.x;                    // 512 wgs
  int wg = (orig & 7) * 64 + (orig >> 3);
  int bm = wg >> 3, bn = wg & 7;
  int m0 = bm << 6, n0 = bn << 7;
  int tid = threadIdx.x;
  int w = tid >> 6, ln = tid & 63;
  int g = ln >> 4, c = ln & 15;
  int wr = w >> 1, wc = w & 1;

  const unsigned short* su[3];
  int du[3];
  #pragma unroll
  for (int i = 0; i < 3; ++i) {
    int u = 3 * w + i;
    if (u < 4) {
      su[i] = A + (size_t)(m0 + u * 16 + (ln >> 2)) * 1024 + (ln & 3) * 8;
      du[i] = u * 512;
    } else {
      int v2 = u - 4;
      su[i] = Bt + (size_t)(n0 + v2 * 16 + (ln >> 2)) * 1024 + (ln & 3) * 8;
      du[i] = 2048 + v2 * 512;
    }
  }

  f32x4 acc[2][4];
  f32x4 zero = {0.f, 0.f, 0.f, 0.f};
  #pragma unroll
  for (int m = 0; m < 2; ++m)
    #pragma unroll
    for (int n = 0; n < 4; ++n) acc[m][n] = zero;

  #pragma unroll
  for (int i = 0; i < 3; ++i) GLD16(su[i], &lds[0][du[i]]);
  __syncthreads();

  int aoff = (wr * 32 + c) * 32 + g * 8;
  int boff = 2048 + (wc * 64 + c) * 32 + g * 8;

  int cur = 0;
  for (int t = 0; t < 32; ++t) {
    if (t < 31) {
      int nb = cur ^ 1;
      #pragma unroll
      for (int i = 0; i < 3; ++i) GLD16(su[i] + (t + 1) * 32, &lds[nb][du[i]]);
    }
    s16x8 af[2], bf[4];
    #pragma unroll
    for (int m = 0; m < 2; ++m)
      af[m] = *(const s16x8*)&lds[cur][aoff + m * 512];
    #pragma unroll
    for (int n = 0; n < 4; ++n)
      bf[n] = *(const s16x8*)&lds[cur][boff + n * 512];
    #pragma unroll
    for (int m = 0; m < 2; ++m)
      #pragma unroll
      for (int n = 0; n < 4; ++n)
        acc[m][n] = mfma32(af[m], bf[n], acc[m][n]);
    __syncthreads();
    cur ^= 1;
  }

  #pragma unroll
  for (int n = 0; n < 4; ++n) {
    int cg = n0 + wc * 64 + n * 16 + c;
    float bias = bo[cg];
    #pragma unroll
    for (int m = 0; m < 2; ++m) {
      int r = m0 + wr * 32 + m * 16 + g * 4;
      out[(size_t)r * 1024 + cg] = acc[m][n][0] + bias;
      out[(size_t)(r + 1) * 1024 + cg] = acc[m][n][1] + bias;
      out[(size_t)(r + 2) * 1024 + cg] = acc[m][n][2] + bias;
      out[(size_t)(r + 3) * 1024 + cg] = acc[m][n][3] + bias;
    }
  }
}

extern "C" void kernel_launch(void* const* d_in, const int* in_sizes, int n_in,
                              void* d_out, int out_size, void* d_ws, size_t ws_size,
                              hipStream_t stream) {
  (void)in_sizes; (void)n_in; (void)out_size; (void)ws_size;
  const float* x  = (const float*)d_in[0];
  const float* Wq = (const float*)d_in[1];
  const float* bq = (const float*)d_in[2];
  const float* Wk = (const float*)d_in[3];
  const float* bk = (const float*)d_in[4];
  const float* Wv = (const float*)d_in[5];
  const float* bv = (const float*)d_in[6];
  const float* Wo = (const float*)d_in[7];
  const float* bo = (const float*)d_in[8];
  float* out = (float*)d_out;
  char* ws = (char*)d_ws;
  unsigned short* xb  = (unsigned short*)(ws);             // [4096][1024] bf16
  unsigned short* Wt  = (unsigned short*)(ws + 8388608);   // [Wq^T|Wk^T|Wv^T|Wo^T]
  unsigned short* Wot = (unsigned short*)(ws + 14680064);  // = Wt + 3*1048576
  unsigned short* qb  = (unsigned short*)(ws + 16777216);  // pre-scaled q
  unsigned short* kfb = (unsigned short*)(ws + 25165824);  // K fragment-order
  unsigned short* vfb = (unsigned short*)(ws + 33554432);  // V paired-fragment-order
  unsigned short* ao  = (unsigned short*)(ws + 41943040);  // [B,S,H,Dh] bf16

  prep<<<2048, 256, 0, stream>>>(x, Wq, Wk, Wv, Wo, xb, Wt);
  qkv_gemm<<<768, 256, 0, stream>>>(xb, Wt, bq, bk, bv, qb, kfb, vfb);
  attn_fwd<<<256, 256, 0, stream>>>(qb, kfb, vfb, ao);
  out_gemm<<<512, 256, 0, stream>>>(ao, Wot, bo, out);
}

// Round 8
// 111.376 us; speedup vs baseline: 1.0552x; 1.0552x over previous
//
#include <hip/hip_runtime.h>
#include <hip/hip_bf16.h>
#include <stdint.h>

using f32x4 = __attribute__((ext_vector_type(4))) float;
using s16x8 = __attribute__((ext_vector_type(8))) short;
using s16x4 = __attribute__((ext_vector_type(4))) short;

__device__ __forceinline__ unsigned short f2bf(float f) {
  union { float f; unsigned int u; } v; v.f = f;
  return (unsigned short)((v.u + 0x7FFFu + ((v.u >> 16) & 1u)) >> 16);
}

__device__ __forceinline__ float exp2_(float x) {
  float r;
  asm("v_exp_f32 %0, %1" : "=v"(r) : "v"(x));
  return r;
}

// pack 4 f32 -> 4 bf16 via 2x v_cvt_pk_bf16_f32
__device__ __forceinline__ s16x4 pk4(float a, float b, float c, float d) {
  union { unsigned u[2]; s16x4 v; } r;
  asm("v_cvt_pk_bf16_f32 %0, %1, %2" : "=v"(r.u[0]) : "v"(a), "v"(b));
  asm("v_cvt_pk_bf16_f32 %0, %1, %2" : "=v"(r.u[1]) : "v"(c), "v"(d));
  return r.v;
}

__device__ __forceinline__ short pbf(float f) {
  __hip_bfloat16 h = __float2bfloat16(f);
  return *(short*)&h;
}

#define GLD16(gp, lp) __builtin_amdgcn_global_load_lds( \
    (const __attribute__((address_space(1))) unsigned int*)(uintptr_t)(gp), \
    (__attribute__((address_space(3))) unsigned int*)(uintptr_t)(lp), 16, 0, 0)

__device__ __forceinline__ f32x4 mfma32(s16x8 a, s16x8 b, f32x4 c) {
  return __builtin_amdgcn_mfma_f32_16x16x32_bf16(a, b, c, 0, 0, 0);
}

#if __has_builtin(__builtin_amdgcn_mfma_f32_16x16x16bf16_1k)
__device__ __forceinline__ f32x4 mfma16(s16x4 a, s16x4 b, f32x4 c) {
  return __builtin_amdgcn_mfma_f32_16x16x16bf16_1k(a, b, c, 0, 0, 0);
}
#else
__device__ __forceinline__ f32x4 mfma16(s16x4 a, s16x4 b, f32x4 c) {
  f32x4 d;
  asm volatile("v_mfma_f32_16x16x16_bf16 %0, %1, %2, %3"
               : "=v"(d) : "v"(a), "v"(b), "v"(c));
  return d;
}
#endif

// ---------------- prep: fused x-convert + 4 weight transposes ----------------
__global__ __launch_bounds__(256)
void prep(const float* __restrict__ x,
          const float* __restrict__ Wq, const float* __restrict__ Wk,
          const float* __restrict__ Wv, const float* __restrict__ Wo,
          unsigned short* __restrict__ xb, unsigned short* __restrict__ Wt) {
  __shared__ float tile[64][65];
  int blk = blockIdx.x;
  int tid = threadIdx.x;
  if (blk < 1024) {
    const float4* xi = (const float4*)x;
    ushort4* xo = (ushort4*)xb;
    #pragma unroll
    for (int j = 0; j < 4; ++j) {
      int i = blk * 1024 + j * 256 + tid;
      float4 v = xi[i];
      ushort4 o;
      o.x = f2bf(v.x); o.y = f2bf(v.y); o.z = f2bf(v.z); o.w = f2bf(v.w);
      xo[i] = o;
    }
  } else {
    int wid = blk - 1024;
    int which = wid >> 8, t = wid & 255;
    const float* W = (which == 0) ? Wq : (which == 1) ? Wk : (which == 2) ? Wv : Wo;
    unsigned short* dst = Wt + (size_t)which * 1048576;
    int k0 = (t & 15) * 64, n0 = (t >> 4) * 64;
    int tx = tid & 63, ty = tid >> 6;
    #pragma unroll
    for (int j = 0; j < 64; j += 4)
      tile[ty + j][tx] = W[(size_t)(k0 + ty + j) * 1024 + n0 + tx];
    __syncthreads();
    #pragma unroll
    for (int j = 0; j < 64; j += 4)
      dst[(size_t)(n0 + ty + j) * 1024 + k0 + tx] = f2bf(tile[tx][ty + j]);
  }
}

// ---------------- fused QKV GEMM: [4096,1024] x [1024,3072] ----------------
// Epilogue writes q:[B,H,S,Dh] (pre-scaled by log2e/8), K in MFMA fragment
// order, and V in PAIRED fragment order (kv-16-tile pairs adjacent -> b128):
//   vfrag2[pair][Tp=kv>>5][dt=dh>>4][lane=g*16+c][par=(kv>>4)&1][e=kv&3]
__global__ __launch_bounds__(256)
void qkv_gemm(const unsigned short* __restrict__ A,
              const unsigned short* __restrict__ Bt,
              const float* __restrict__ bq, const float* __restrict__ bk,
              const float* __restrict__ bv,
              unsigned short* __restrict__ qo, unsigned short* __restrict__ kf,
              unsigned short* __restrict__ vf) {
  __shared__ unsigned short ldsA[2][4096];
  __shared__ unsigned short ldsB[2][4096];
  int orig = blockIdx.x;                    // 768 wgs
  int wg = (orig & 7) * 96 + (orig >> 3);
  int bm = wg / 24;
  int bn = wg - bm * 24;
  int m0 = bm << 7, n0 = bn << 7;
  int tid = threadIdx.x;
  int w = tid >> 6, ln = tid & 63;
  int g = ln >> 4, c = ln & 15;
  int wr = w >> 1, wc = w & 1;

  const unsigned short* ga = A + (size_t)(m0 + (tid >> 2)) * 1024 + (tid & 3) * 8;
  const unsigned short* gb = Bt + (size_t)(n0 + (tid >> 2)) * 1024 + (tid & 3) * 8;
  int lb = w * 512;

  f32x4 acc[4][4];
  f32x4 zero = {0.f, 0.f, 0.f, 0.f};
  #pragma unroll
  for (int m = 0; m < 4; ++m)
    #pragma unroll
    for (int n = 0; n < 4; ++n) acc[m][n] = zero;

  GLD16(ga, &ldsA[0][lb]);
  GLD16(ga + 65536, &ldsA[0][2048 + lb]);
  GLD16(gb, &ldsB[0][lb]);
  GLD16(gb + 65536, &ldsB[0][2048 + lb]);
  __syncthreads();

  int aoff = (wr * 64 + c) * 32 + g * 8;
  int boff = (wc * 64 + c) * 32 + g * 8;

  int cur = 0;
  for (int t = 0; t < 32; ++t) {
    if (t < 31) {
      const unsigned short* ga2 = ga + (t + 1) * 32;
      const unsigned short* gb2 = gb + (t + 1) * 32;
      int nb = cur ^ 1;
      GLD16(ga2, &ldsA[nb][lb]);
      GLD16(ga2 + 65536, &ldsA[nb][2048 + lb]);
      GLD16(gb2, &ldsB[nb][lb]);
      GLD16(gb2 + 65536, &ldsB[nb][2048 + lb]);
    }
    s16x8 af[4], bf[4];
    #pragma unroll
    for (int m = 0; m < 4; ++m)
      af[m] = *(const s16x8*)&ldsA[cur][aoff + m * 512];
    #pragma unroll
    for (int n = 0; n < 4; ++n)
      bf[n] = *(const s16x8*)&ldsB[cur][boff + n * 512];
    #pragma unroll
    for (int m = 0; m < 4; ++m)
      #pragma unroll
      for (int n = 0; n < 4; ++n)
        acc[m][n] = mfma32(af[m], bf[n], acc[m][n]);
    __syncthreads();
    cur ^= 1;
  }

  #pragma unroll
  for (int n = 0; n < 4; ++n) {
    int cg = n0 + wc * 64 + n * 16 + c;     // 0..3071
    int p = cg >> 10;                       // 0=q 1=k 2=v
    int d = cg & 1023;
    int hh = d >> 6, dh = d & 63;
    const float* bp = (p == 0) ? bq : (p == 1) ? bk : bv;
    float bias = bp[d];
    #pragma unroll
    for (int m = 0; m < 4; ++m) {
      int r = m0 + wr * 64 + m * 16 + g * 4;  // rows r..r+3 (e=0..3)
      int b = r >> 11, s = r & 2047;
      size_t pv = (size_t)((b << 4) + hh);
      if (p == 2) {
        int T = s >> 4;                     // kv 16-tile; s&15 == g*4 + e
        int Tp = T >> 1, par = T & 1;
        int dtp = dh >> 4;                  // dh&15 == c
        ushort4 pk;
        pk.x = f2bf(acc[m][n][0] + bias);
        pk.y = f2bf(acc[m][n][1] + bias);
        pk.z = f2bf(acc[m][n][2] + bias);
        pk.w = f2bf(acc[m][n][3] + bias);
        *(ushort4*)&vf[pv * 131072 +
                       (size_t)(((Tp * 4 + dtp) * 64 + g * 16 + c) * 8 + par * 4)] = pk;
      } else if (p == 1) {
        int T = s >> 4;
        int h2 = dh >> 5, gp = (dh >> 3) & 3, j = dh & 7;
        unsigned short* kd = kf + pv * 131072 + T * 1024 + h2 * 512 +
                             (gp * 16 + (s & 15)) * 8 + j;
        kd[0]  = f2bf(acc[m][n][0] + bias);
        kd[8]  = f2bf(acc[m][n][1] + bias);
        kd[16] = f2bf(acc[m][n][2] + bias);
        kd[24] = f2bf(acc[m][n][3] + bias);
      } else {
        const float sc = 0.180336880111120f;  // 1/8 * log2(e)
        size_t base = (pv * 2048 + s) * 64 + dh;
        qo[base]       = f2bf((acc[m][n][0] + bias) * sc);
        qo[base + 64]  = f2bf((acc[m][n][1] + bias) * sc);
        qo[base + 128] = f2bf((acc[m][n][2] + bias) * sc);
        qo[base + 192] = f2bf((acc[m][n][3] + bias) * sc);
      }
    }
  }
}

// ---------------- flash attention (tri-buffer, cross-iter PV pipeline) -------
// R6 geometry: 4 waves x 32 q-rows (j=0,1), KVB=64, 512 wgs (2 blocks/CU).
// T15-style pipeline: per iter issue QK(t) MFMA, then PV(t-1) MFMA (independent
// -> fills the QK drain), then exp2/pack(t). Tri-buffered LDS (3 x 16KB): cur
// holds tile t, prev holds t-1's V (read by PV), next receives tile t+1's
// stage. Stage is issued after the previous iter's end-barrier, so no wave
// can still be reading the buffer being overwritten. Counted vmcnt(4) keeps
// the in-flight stage across barriers. Fixed-max softmax (log2-domain logits,
// shift-invariant). pa ping-pong via even/odd unroll (all static indices).
__global__ __launch_bounds__(256, 2)
void attn_fwd(const unsigned short* __restrict__ q,
              const unsigned short* __restrict__ kfb,
              const unsigned short* __restrict__ vfb,
              unsigned short* __restrict__ ao) {
  __shared__ unsigned short ldsKV[3][8192];  // per buffer: K 0..4095, V 4096..8191
  int orig = blockIdx.x;                    // 512 wgs
  int wg = (orig & 7) * 64 + (orig >> 3);   // XCD-contiguous
  int pair = wg >> 4, qt = wg & 15;         // 16 blocks (128 q-rows) per pair
  int tid = threadIdx.x;
  int w = tid >> 6, ln = tid & 63;
  int g = ln >> 4, c = ln & 15;
  int q0 = qt * 128 + w * 32;
  const unsigned short* qp = q + (size_t)pair * 131072;
  const char* kbase = (const char*)(kfb + (size_t)pair * 131072);
  const char* vbase = (const char*)(vfb + (size_t)pair * 131072);

  // staging: waves 0,1 -> K halves, waves 2,3 -> V halves; 4KB each
  const char* ssrc = ((w < 2) ? kbase : vbase) + (w & 1) * 4096;
  int dsto = (w >= 2 ? 8192 : 0) + (w & 1) * 4096;  // bytes within one buffer

  s16x8 qf[2][2];
  #pragma unroll
  for (int j = 0; j < 2; ++j)
    #pragma unroll
    for (int h = 0; h < 2; ++h)
      qf[j][h] = *(const s16x8*)&qp[(q0 + j * 16 + c) * 64 + h * 32 + g * 8];

  f32x4 acc[2][4];
  f32x4 zero = {0.f, 0.f, 0.f, 0.f};
  #pragma unroll
  for (int j = 0; j < 2; ++j)
    #pragma unroll
    for (int dt = 0; dt < 4; ++dt) acc[j][dt] = zero;
  float l0 = 0.f, l1 = 0.f;

  // prologue: stage tile 0 into buffer 0
  #pragma unroll
  for (int j = 0; j < 4; ++j)
    GLD16(ssrc + j * 1024 + ln * 16, (char*)&ldsKV[0][0] + dsto + j * 1024);

  const unsigned short* L0 = ldsKV[0];
  const unsigned short* L1 = ldsKV[1];
  const unsigned short* L2 = ldsKV[2];
  s16x4 paA[2][4], paB[2][4];

  // one pipeline iteration: cur=LC holds tile T; PV of tile T-1 from LP using
  // PAP; stage tile T+1 into LN; write PAC for tile T.
#define ATTN_ITER(T, LC, LP, LN, PAC, PAP)                                     \
  {                                                                            \
    if ((T) < 31) {                                                            \
      const char* s2 = ssrc + ((T) + 1) * 8192;                                \
      char* d2 = (char*)(LN) + dsto;                                           \
      _Pragma("unroll")                                                        \
      for (int j = 0; j < 4; ++j)                                              \
        GLD16(s2 + j * 1024 + ln * 16, d2 + j * 1024);                         \
      asm volatile("s_waitcnt vmcnt(4)" ::: "memory");                         \
    } else {                                                                   \
      asm volatile("s_waitcnt vmcnt(0)" ::: "memory");                         \
    }                                                                          \
    __builtin_amdgcn_s_barrier();                                              \
    /* K fragments of tile T (stride-1 b128) */                                \
    s16x8 kc[4][2];                                                            \
    _Pragma("unroll")                                                          \
    for (int kt = 0; kt < 4; ++kt) {                                           \
      kc[kt][0] = *(const s16x8*)&(LC)[kt * 1024 + ln * 8];                    \
      kc[kt][1] = *(const s16x8*)&(LC)[kt * 1024 + 512 + ln * 8];              \
    }                                                                          \
    f32x4 st[4][2];                                                            \
    __builtin_amdgcn_s_setprio(1);                                             \
    _Pragma("unroll")                                                          \
    for (int kt = 0; kt < 4; ++kt)                                             \
      _Pragma("unroll")                                                        \
      for (int j = 0; j < 2; ++j) {                                            \
        f32x4 t2 = zero;                                                       \
        t2 = mfma32(kc[kt][0], qf[j][0], t2);                                  \
        t2 = mfma32(kc[kt][1], qf[j][1], t2);                                  \
        st[kt][j] = t2;                                                        \
      }                                                                        \
    __builtin_amdgcn_s_setprio(0);                                             \
    /* PV of tile T-1 (independent of st -> fills the QK drain) */             \
    if ((T) > 0) {                                                             \
      __builtin_amdgcn_s_setprio(1);                                           \
      _Pragma("unroll")                                                        \
      for (int dt = 0; dt < 4; ++dt)                                           \
        _Pragma("unroll")                                                      \
        for (int tp = 0; tp < 2; ++tp) {                                       \
          s16x8 vv = *(const s16x8*)&(LP)[4096 + tp * 2048 + dt * 512 + ln * 8]; \
          s16x4 vlo = __builtin_shufflevector(vv, vv, 0, 1, 2, 3);             \
          s16x4 vhi = __builtin_shufflevector(vv, vv, 4, 5, 6, 7);             \
          _Pragma("unroll")                                                    \
          for (int j = 0; j < 2; ++j) {                                        \
            acc[j][dt] = mfma16((PAP)[j][tp * 2], vlo, acc[j][dt]);            \
            acc[j][dt] = mfma16((PAP)[j][tp * 2 + 1], vhi, acc[j][dt]);        \
          }                                                                    \
        }                                                                      \
      __builtin_amdgcn_s_setprio(0);                                           \
    }                                                                          \
    /* P(T) = exp2(S), pack, lane-local l partials */                          \
    _Pragma("unroll")                                                          \
    for (int kt = 0; kt < 4; ++kt) {                                           \
      float p00 = exp2_(st[kt][0][0]), p01 = exp2_(st[kt][0][1]);              \
      float p02 = exp2_(st[kt][0][2]), p03 = exp2_(st[kt][0][3]);              \
      float p10 = exp2_(st[kt][1][0]), p11 = exp2_(st[kt][1][1]);              \
      float p12 = exp2_(st[kt][1][2]), p13 = exp2_(st[kt][1][3]);              \
      l0 += (p00 + p01) + (p02 + p03);                                         \
      l1 += (p10 + p11) + (p12 + p13);                                         \
      (PAC)[0][kt] = pk4(p00, p01, p02, p03);                                  \
      (PAC)[1][kt] = pk4(p10, p11, p12, p13);                                  \
    }                                                                          \
    __builtin_amdgcn_s_barrier();                                              \
  }

  for (int t = 0; t < 32; t += 2) {
    ATTN_ITER(t,     L0, L2, L1, paA, paB);
    ATTN_ITER(t + 1, L1, L0, L2, paB, paA);
    const unsigned short* tmp = L2;  // rotate (L0,L1,L2) <- (L2,L0,L1)
    L2 = L1; L1 = L0; L0 = tmp;
  }
#undef ATTN_ITER

  // final PV(31): tile 31 lives in (post-rotation) L2; pa = paB
  __builtin_amdgcn_s_setprio(1);
  #pragma unroll
  for (int dt = 0; dt < 4; ++dt)
    #pragma unroll
    for (int tp = 0; tp < 2; ++tp) {
      s16x8 vv = *(const s16x8*)&L2[4096 + tp * 2048 + dt * 512 + ln * 8];
      s16x4 vlo = __builtin_shufflevector(vv, vv, 0, 1, 2, 3);
      s16x4 vhi = __builtin_shufflevector(vv, vv, 4, 5, 6, 7);
      #pragma unroll
      for (int j = 0; j < 2; ++j) {
        acc[j][dt] = mfma16(paB[j][tp * 2], vlo, acc[j][dt]);
        acc[j][dt] = mfma16(paB[j][tp * 2 + 1], vhi, acc[j][dt]);
      }
    }
  __builtin_amdgcn_s_setprio(0);

  // final l reduction across the 4 g-copies of each q-column
  l0 += __shfl_xor(l0, 16); l0 += __shfl_xor(l0, 32);
  l1 += __shfl_xor(l1, 16); l1 += __shfl_xor(l1, 32);
  float li0 = 1.f / l0, li1 = 1.f / l1;
  int b = pair >> 4, hh = pair & 15;
  #pragma unroll
  for (int e = 0; e < 4; ++e) {
    float i0 = __shfl(li0, g * 4 + e);
    float i1 = __shfl(li1, g * 4 + e);
    size_t r0 = ((size_t)(b * 2048 + q0 + g * 4 + e) * 16 + hh) * 64;
    size_t r1 = ((size_t)(b * 2048 + q0 + 16 + g * 4 + e) * 16 + hh) * 64;
    #pragma unroll
    for (int dt = 0; dt < 4; ++dt) {
      ao[r0 + dt * 16 + c] = (unsigned short)pbf(acc[0][dt][e] * i0);
      ao[r1 + dt * 16 + c] = (unsigned short)pbf(acc[1][dt][e] * i1);
    }
  }
}

// ---------------- output GEMM: ao[4096,1024] x Wo -> fp32 out ----------------
__global__ __launch_bounds__(256)
void out_gemm(const unsigned short* __restrict__ A,
              const unsigned short* __restrict__ Bt,
              const float* __restrict__ bo, float* __restrict__ out) {
  __shared__ unsigned short lds[2][6144];   // A @0..2047, B @2048..6143
  int orig = blockIdx.x;                    // 512 wgs
  int wg = (orig & 7) * 64 + (orig >> 3);
  int bm = wg >> 3, bn = wg & 7;
  int m0 = bm << 6, n0 = bn << 7;
  int tid = threadIdx.x;
  int w = tid >> 6, ln = tid & 63;
  int g = ln >> 4, c = ln & 15;
  int wr = w >> 1, wc = w & 1;

  const unsigned short* su[3];
  int du[3];
  #pragma unroll
  for (int i = 0; i < 3; ++i) {
    int u = 3 * w + i;
    if (u < 4) {
      su[i] = A + (size_t)(m0 + u * 16 + (ln >> 2)) * 1024 + (ln & 3) * 8;
      du[i] = u * 512;
    } else {
      int v2 = u - 4;
      su[i] = Bt + (size_t)(n0 + v2 * 16 + (ln >> 2)) * 1024 + (ln & 3) * 8;
      du[i] = 2048 + v2 * 512;
    }
  }

  f32x4 acc[2][4];
  f32x4 zero = {0.f, 0.f, 0.f, 0.f};
  #pragma unroll
  for (int m = 0; m < 2; ++m)
    #pragma unroll
    for (int n = 0; n < 4; ++n) acc[m][n] = zero;

  #pragma unroll
  for (int i = 0; i < 3; ++i) GLD16(su[i], &lds[0][du[i]]);
  __syncthreads();

  int aoff = (wr * 32 + c) * 32 + g * 8;
  int boff = 2048 + (wc * 64 + c) * 32 + g * 8;

  int cur = 0;
  for (int t = 0; t < 32; ++t) {
    if (t < 31) {
      int nb = cur ^ 1;
      #pragma unroll
      for (int i = 0; i < 3; ++i) GLD16(su[i] + (t + 1) * 32, &lds[nb][du[i]]);
    }
    s16x8 af[2], bf[4];
    #pragma unroll
    for (int m = 0; m < 2; ++m)
      af[m] = *(const s16x8*)&lds[cur][aoff + m * 512];
    #pragma unroll
    for (int n = 0; n < 4; ++n)
      bf[n] = *(const s16x8*)&lds[cur][boff + n * 512];
    #pragma unroll
    for (int m = 0; m < 2; ++m)
      #pragma unroll
      for (int n = 0; n < 4; ++n)
        acc[m][n] = mfma32(af[m], bf[n], acc[m][n]);
    __syncthreads();
    cur ^= 1;
  }

  #pragma unroll
  for (int n = 0; n < 4; ++n) {
    int cg = n0 + wc * 64 + n * 16 + c;
    float bias = bo[cg];
    #pragma unroll
    for (int m = 0; m < 2; ++m) {
      int r = m0 + wr * 32 + m * 16 + g * 4;
      out[(size_t)r * 1024 + cg] = acc[m][n][0] + bias;
      out[(size_t)(r + 1) * 1024 + cg] = acc[m][n][1] + bias;
      out[(size_t)(r + 2) * 1024 + cg] = acc[m][n][2] + bias;
      out[(size_t)(r + 3) * 1024 + cg] = acc[m][n][3] + bias;
    }
  }
}

extern "C" void kernel_launch(void* const* d_in, const int* in_sizes, int n_in,
                              void* d_out, int out_size, void* d_ws, size_t ws_size,
                              hipStream_t stream) {
  (void)in_sizes; (void)n_in; (void)out_size; (void)ws_size;
  const float* x  = (const float*)d_in[0];
  const float* Wq = (const float*)d_in[1];
  const float* bq = (const float*)d_in[2];
  const float* Wk = (const float*)d_in[3];
  const float* bk = (const float*)d_in[4];
  const float* Wv = (const float*)d_in[5];
  const float* bv = (const float*)d_in[6];
  const float* Wo = (const float*)d_in[7];
  const float* bo = (const float*)d_in[8];
  float* out = (float*)d_out;
  char* ws = (char*)d_ws;
  unsigned short* xb  = (unsigned short*)(ws);             // [4096][1024] bf16
  unsigned short* Wt  = (unsigned short*)(ws + 8388608);   // [Wq^T|Wk^T|Wv^T|Wo^T]
  unsigned short* Wot = (unsigned short*)(ws + 14680064);  // = Wt + 3*1048576
  unsigned short* qb  = (unsigned short*)(ws + 16777216);  // pre-scaled q
  unsigned short* kfb = (unsigned short*)(ws + 25165824);  // K fragment-order
  unsigned short* vfb = (unsigned short*)(ws + 33554432);  // V paired-fragment-order
  unsigned short* ao  = (unsigned short*)(ws + 41943040);  // [B,S,H,Dh] bf16

  prep<<<2048, 256, 0, stream>>>(x, Wq, Wk, Wv, Wo, xb, Wt);
  qkv_gemm<<<768, 256, 0, stream>>>(xb, Wt, bq, bk, bv, qb, kfb, vfb);
  attn_fwd<<<512, 256, 0, stream>>>(qb, kfb, vfb, ao);
  out_gemm<<<512, 256, 0, stream>>>(ao, Wot, bo, out);
}

// Round 9
// 105.116 us; speedup vs baseline: 1.1180x; 1.0596x over previous
//
#include <hip/hip_runtime.h>
#include <hip/hip_bf16.h>
#include <stdint.h>

using f32x4 = __attribute__((ext_vector_type(4))) float;
using s16x8 = __attribute__((ext_vector_type(8))) short;
using s16x4 = __attribute__((ext_vector_type(4))) short;

__device__ __forceinline__ unsigned short f2bf(float f) {
  union { float f; unsigned int u; } v; v.f = f;
  return (unsigned short)((v.u + 0x7FFFu + ((v.u >> 16) & 1u)) >> 16);
}

__device__ __forceinline__ float exp2_(float x) {
  float r;
  asm("v_exp_f32 %0, %1" : "=v"(r) : "v"(x));
  return r;
}

// pack 4 f32 -> 4 bf16 via 2x v_cvt_pk_bf16_f32
__device__ __forceinline__ s16x4 pk4(float a, float b, float c, float d) {
  union { unsigned u[2]; s16x4 v; } r;
  asm("v_cvt_pk_bf16_f32 %0, %1, %2" : "=v"(r.u[0]) : "v"(a), "v"(b));
  asm("v_cvt_pk_bf16_f32 %0, %1, %2" : "=v"(r.u[1]) : "v"(c), "v"(d));
  return r.v;
}

__device__ __forceinline__ short pbf(float f) {
  __hip_bfloat16 h = __float2bfloat16(f);
  return *(short*)&h;
}

#define GLD16(gp, lp) __builtin_amdgcn_global_load_lds( \
    (const __attribute__((address_space(1))) unsigned int*)(uintptr_t)(gp), \
    (__attribute__((address_space(3))) unsigned int*)(uintptr_t)(lp), 16, 0, 0)

__device__ __forceinline__ f32x4 mfma32(s16x8 a, s16x8 b, f32x4 c) {
  return __builtin_amdgcn_mfma_f32_16x16x32_bf16(a, b, c, 0, 0, 0);
}

#if __has_builtin(__builtin_amdgcn_mfma_f32_16x16x16bf16_1k)
__device__ __forceinline__ f32x4 mfma16(s16x4 a, s16x4 b, f32x4 c) {
  return __builtin_amdgcn_mfma_f32_16x16x16bf16_1k(a, b, c, 0, 0, 0);
}
#else
__device__ __forceinline__ f32x4 mfma16(s16x4 a, s16x4 b, f32x4 c) {
  f32x4 d;
  asm volatile("v_mfma_f32_16x16x16_bf16 %0, %1, %2, %3"
               : "=v"(d) : "v"(a), "v"(b), "v"(c));
  return d;
}
#endif

// ---------------- prep: fused x-convert + 4 weight transposes ----------------
__global__ __launch_bounds__(256)
void prep(const float* __restrict__ x,
          const float* __restrict__ Wq, const float* __restrict__ Wk,
          const float* __restrict__ Wv, const float* __restrict__ Wo,
          unsigned short* __restrict__ xb, unsigned short* __restrict__ Wt) {
  __shared__ float tile[64][65];
  int blk = blockIdx.x;
  int tid = threadIdx.x;
  if (blk < 1024) {
    const float4* xi = (const float4*)x;
    ushort4* xo = (ushort4*)xb;
    #pragma unroll
    for (int j = 0; j < 4; ++j) {
      int i = blk * 1024 + j * 256 + tid;
      float4 v = xi[i];
      ushort4 o;
      o.x = f2bf(v.x); o.y = f2bf(v.y); o.z = f2bf(v.z); o.w = f2bf(v.w);
      xo[i] = o;
    }
  } else {
    int wid = blk - 1024;
    int which = wid >> 8, t = wid & 255;
    const float* W = (which == 0) ? Wq : (which == 1) ? Wk : (which == 2) ? Wv : Wo;
    unsigned short* dst = Wt + (size_t)which * 1048576;
    int k0 = (t & 15) * 64, n0 = (t >> 4) * 64;
    int tx = tid & 63, ty = tid >> 6;
    #pragma unroll
    for (int j = 0; j < 64; j += 4)
      tile[ty + j][tx] = W[(size_t)(k0 + ty + j) * 1024 + n0 + tx];
    __syncthreads();
    #pragma unroll
    for (int j = 0; j < 64; j += 4)
      dst[(size_t)(n0 + ty + j) * 1024 + k0 + tx] = f2bf(tile[tx][ty + j]);
  }
}

// ---------------- fused QKV GEMM: 256x256 tile, 8 waves, BK=64 ---------------
// [4096,1024] x [1024,3072]. One 512-thread block per CU (LDS 128KB dbuf).
// Per K-tile: stage K-tile t+1 into buf^1 early (8 x global_load_lds, linear
// dest, PRE-SWIZZLED global source: byte ^= ((row&7)<<4) within each 128B
// row); 4 quadrant phases of {swizzled ds_read_b128 frags + 16 mfma}; one
// vmcnt(0)+barrier per K-tile (drains loads issued ~2500cyc earlier => ~free).
// Epilogue: +bias, q pre-scaled by log2e/8, K fragment-order, V paired
// fragment-order (same formulas as before, wave=128x64 geometry).
__global__ __launch_bounds__(512, 2)
void qkv_gemm(const unsigned short* __restrict__ A,
              const unsigned short* __restrict__ Bt,
              const float* __restrict__ bq, const float* __restrict__ bk,
              const float* __restrict__ bv,
              unsigned short* __restrict__ qo, unsigned short* __restrict__ kf,
              unsigned short* __restrict__ vf) {
  __shared__ unsigned short lds2[2][32768];   // per buf: A0|A1|B0|B1, 16KB each
  int orig = blockIdx.x;                      // 192 wgs (192%8==0)
  int wg = (orig & 7) * 24 + (orig >> 3);
  int bm = wg / 12, bn = wg % 12;
  int m0 = bm << 8, n0 = bn << 8;
  int tid = threadIdx.x;
  int w = tid >> 6, ln = tid & 63;
  int g = ln >> 4, c = ln & 15;
  int wm = w >> 2, wn = w & 3;                // 2M x 4N waves

  // staging source: thread t covers LDS bytes o = i*8192 + t*16 of a 16KB
  // half-tile; row rr = o>>7 = i*64 + (t>>3); pre-swizzled col:
  int rrs = tid >> 3;
  int lcol = (((tid & 7) ^ ((tid >> 3) & 7)) << 4);
  const char* pA = (const char*)A + (size_t)(m0 + rrs) * 2048 + lcol;
  const char* pB = (const char*)Bt + (size_t)(n0 + rrs) * 2048 + lcol;
  int woff = w * 1024;                        // wave-uniform dest offset

  // stage all 4 half-tiles (A0,A1,B0,B1) of K-tile kt into buf
#define QKV_STAGE(buf, kt)                                                     \
  {                                                                            \
    char* db = (char*)&lds2[buf][0];                                           \
    _Pragma("unroll")                                                          \
    for (int h = 0; h < 2; ++h)                                                \
      _Pragma("unroll")                                                        \
      for (int i = 0; i < 2; ++i) {                                            \
        GLD16(pA + (size_t)(h * 128 + i * 64) * 2048 + (kt) * 128,             \
              db + h * 16384 + i * 8192 + woff);                               \
        GLD16(pB + (size_t)(h * 128 + i * 64) * 2048 + (kt) * 128,             \
              db + 32768 + h * 16384 + i * 8192 + woff);                       \
      }                                                                        \
  }

  int cs = (c & 7) << 4;                      // read-side swizzle term
  // fragment read: L = half base (ushort*), row within half, kk in {0,1}
#define DSF(Lp, row, kk) \
  (*(const s16x8*)&(Lp)[(row) * 64 + ((((kk) * 64 + g * 16) ^ cs) >> 1)])

  f32x4 acc[8][4];
  f32x4 zero = {0.f, 0.f, 0.f, 0.f};
  #pragma unroll
  for (int mi = 0; mi < 8; ++mi)
    #pragma unroll
    for (int ni = 0; ni < 4; ++ni) acc[mi][ni] = zero;

  QKV_STAGE(0, 0);
  asm volatile("s_waitcnt vmcnt(0)" ::: "memory");
  __builtin_amdgcn_s_barrier();

  for (int kt = 0; kt < 16; ++kt) {
    int bsel = kt & 1;
    const unsigned short* LA = &lds2[bsel][wm * 8192];
    const unsigned short* LB = &lds2[bsel][16384 + (wn >> 1) * 8192];
    int rB = (wn & 1) * 64;
    if (kt < 15) QKV_STAGE(bsel ^ 1, kt + 1);

    s16x8 a[4][2], b0[2][2], b1[2][2];
    // p1: quad (mi 0-3) x (ni 0-1)
    #pragma unroll
    for (int mi = 0; mi < 4; ++mi) {
      a[mi][0] = DSF(LA, mi * 16 + c, 0);
      a[mi][1] = DSF(LA, mi * 16 + c, 1);
    }
    #pragma unroll
    for (int ni = 0; ni < 2; ++ni) {
      b0[ni][0] = DSF(LB, rB + ni * 16 + c, 0);
      b0[ni][1] = DSF(LB, rB + ni * 16 + c, 1);
    }
    #pragma unroll
    for (int mi = 0; mi < 4; ++mi)
      #pragma unroll
      for (int ni = 0; ni < 2; ++ni) {
        acc[mi][ni] = mfma32(a[mi][0], b0[ni][0], acc[mi][ni]);
        acc[mi][ni] = mfma32(a[mi][1], b0[ni][1], acc[mi][ni]);
      }
    // p2: quad (mi 4-7) x (ni 0-1)
    #pragma unroll
    for (int mi = 0; mi < 4; ++mi) {
      a[mi][0] = DSF(LA, (mi + 4) * 16 + c, 0);
      a[mi][1] = DSF(LA, (mi + 4) * 16 + c, 1);
    }
    #pragma unroll
    for (int mi = 0; mi < 4; ++mi)
      #pragma unroll
      for (int ni = 0; ni < 2; ++ni) {
        acc[mi + 4][ni] = mfma32(a[mi][0], b0[ni][0], acc[mi + 4][ni]);
        acc[mi + 4][ni] = mfma32(a[mi][1], b0[ni][1], acc[mi + 4][ni]);
      }
    // p3: quad (mi 4-7) x (ni 2-3)
    #pragma unroll
    for (int ni = 0; ni < 2; ++ni) {
      b1[ni][0] = DSF(LB, rB + (ni + 2) * 16 + c, 0);
      b1[ni][1] = DSF(LB, rB + (ni + 2) * 16 + c, 1);
    }
    #pragma unroll
    for (int mi = 0; mi < 4; ++mi)
      #pragma unroll
      for (int ni = 0; ni < 2; ++ni) {
        acc[mi + 4][ni + 2] = mfma32(a[mi][0], b1[ni][0], acc[mi + 4][ni + 2]);
        acc[mi + 4][ni + 2] = mfma32(a[mi][1], b1[ni][1], acc[mi + 4][ni + 2]);
      }
    // p4: quad (mi 0-3) x (ni 2-3) (reload A-quad0)
    #pragma unroll
    for (int mi = 0; mi < 4; ++mi) {
      a[mi][0] = DSF(LA, mi * 16 + c, 0);
      a[mi][1] = DSF(LA, mi * 16 + c, 1);
    }
    #pragma unroll
    for (int mi = 0; mi < 4; ++mi)
      #pragma unroll
      for (int ni = 0; ni < 2; ++ni) {
        acc[mi][ni + 2] = mfma32(a[mi][0], b1[ni][0], acc[mi][ni + 2]);
        acc[mi][ni + 2] = mfma32(a[mi][1], b1[ni][1], acc[mi][ni + 2]);
      }

    asm volatile("s_waitcnt vmcnt(0)" ::: "memory");
    __builtin_amdgcn_s_barrier();
  }
#undef QKV_STAGE
#undef DSF

  // epilogue: identical scatter math, wave = 128x64 output
  #pragma unroll
  for (int ni = 0; ni < 4; ++ni) {
    int cg = n0 + wn * 64 + ni * 16 + c;    // 0..3071
    int p = cg >> 10;                        // 0=q 1=k 2=v
    int d = cg & 1023;
    int hh = d >> 6, dh = d & 63;
    const float* bp = (p == 0) ? bq : (p == 1) ? bk : bv;
    float bias = bp[d];
    #pragma unroll
    for (int mi = 0; mi < 8; ++mi) {
      int r = m0 + wm * 128 + mi * 16 + g * 4;  // rows r..r+3 (e=0..3)
      int b2 = r >> 11, s = r & 2047;
      size_t pv = (size_t)((b2 << 4) + hh);
      if (p == 2) {
        int T = s >> 4;
        int Tp = T >> 1, par = T & 1;
        int dtp = dh >> 4;
        ushort4 pk;
        pk.x = f2bf(acc[mi][ni][0] + bias);
        pk.y = f2bf(acc[mi][ni][1] + bias);
        pk.z = f2bf(acc[mi][ni][2] + bias);
        pk.w = f2bf(acc[mi][ni][3] + bias);
        *(ushort4*)&vf[pv * 131072 +
                       (size_t)(((Tp * 4 + dtp) * 64 + g * 16 + c) * 8 + par * 4)] = pk;
      } else if (p == 1) {
        int T = s >> 4;
        int h2 = dh >> 5, gp = (dh >> 3) & 3, j = dh & 7;
        unsigned short* kd = kf + pv * 131072 + T * 1024 + h2 * 512 +
                             (gp * 16 + (s & 15)) * 8 + j;
        kd[0]  = f2bf(acc[mi][ni][0] + bias);
        kd[8]  = f2bf(acc[mi][ni][1] + bias);
        kd[16] = f2bf(acc[mi][ni][2] + bias);
        kd[24] = f2bf(acc[mi][ni][3] + bias);
      } else {
        const float sc = 0.180336880111120f;  // 1/8 * log2(e)
        size_t base = (pv * 2048 + s) * 64 + dh;
        qo[base]       = f2bf((acc[mi][ni][0] + bias) * sc);
        qo[base + 64]  = f2bf((acc[mi][ni][1] + bias) * sc);
        qo[base + 128] = f2bf((acc[mi][ni][2] + bias) * sc);
        qo[base + 192] = f2bf((acc[mi][ni][3] + bias) * sc);
      }
    }
  }
}

// ---------------- flash attention (tri-buffer, cross-iter PV pipeline) -------
__global__ __launch_bounds__(256, 2)
void attn_fwd(const unsigned short* __restrict__ q,
              const unsigned short* __restrict__ kfb,
              const unsigned short* __restrict__ vfb,
              unsigned short* __restrict__ ao) {
  __shared__ unsigned short ldsKV[3][8192];  // per buffer: K 0..4095, V 4096..8191
  int orig = blockIdx.x;                    // 512 wgs
  int wg = (orig & 7) * 64 + (orig >> 3);   // XCD-contiguous
  int pair = wg >> 4, qt = wg & 15;         // 16 blocks (128 q-rows) per pair
  int tid = threadIdx.x;
  int w = tid >> 6, ln = tid & 63;
  int g = ln >> 4, c = ln & 15;
  int q0 = qt * 128 + w * 32;
  const unsigned short* qp = q + (size_t)pair * 131072;
  const char* kbase = (const char*)(kfb + (size_t)pair * 131072);
  const char* vbase = (const char*)(vfb + (size_t)pair * 131072);

  // staging: waves 0,1 -> K halves, waves 2,3 -> V halves; 4KB each
  const char* ssrc = ((w < 2) ? kbase : vbase) + (w & 1) * 4096;
  int dsto = (w >= 2 ? 8192 : 0) + (w & 1) * 4096;  // bytes within one buffer

  s16x8 qf[2][2];
  #pragma unroll
  for (int j = 0; j < 2; ++j)
    #pragma unroll
    for (int h = 0; h < 2; ++h)
      qf[j][h] = *(const s16x8*)&qp[(q0 + j * 16 + c) * 64 + h * 32 + g * 8];

  f32x4 acc[2][4];
  f32x4 zero = {0.f, 0.f, 0.f, 0.f};
  #pragma unroll
  for (int j = 0; j < 2; ++j)
    #pragma unroll
    for (int dt = 0; dt < 4; ++dt) acc[j][dt] = zero;
  float l0 = 0.f, l1 = 0.f;

  // prologue: stage tile 0 into buffer 0
  #pragma unroll
  for (int j = 0; j < 4; ++j)
    GLD16(ssrc + j * 1024 + ln * 16, (char*)&ldsKV[0][0] + dsto + j * 1024);

  const unsigned short* L0 = ldsKV[0];
  const unsigned short* L1 = ldsKV[1];
  const unsigned short* L2 = ldsKV[2];
  s16x4 paA[2][4], paB[2][4];

#define ATTN_ITER(T, LC, LP, LN, PAC, PAP)                                     \
  {                                                                            \
    if ((T) < 31) {                                                            \
      const char* s2 = ssrc + ((T) + 1) * 8192;                                \
      char* d2 = (char*)(LN) + dsto;                                           \
      _Pragma("unroll")                                                        \
      for (int j = 0; j < 4; ++j)                                              \
        GLD16(s2 + j * 1024 + ln * 16, d2 + j * 1024);                         \
      asm volatile("s_waitcnt vmcnt(4)" ::: "memory");                         \
    } else {                                                                   \
      asm volatile("s_waitcnt vmcnt(0)" ::: "memory");                         \
    }                                                                          \
    __builtin_amdgcn_s_barrier();                                              \
    s16x8 kc[4][2];                                                            \
    _Pragma("unroll")                                                          \
    for (int kt = 0; kt < 4; ++kt) {                                           \
      kc[kt][0] = *(const s16x8*)&(LC)[kt * 1024 + ln * 8];                    \
      kc[kt][1] = *(const s16x8*)&(LC)[kt * 1024 + 512 + ln * 8];              \
    }                                                                          \
    f32x4 st[4][2];                                                            \
    __builtin_amdgcn_s_setprio(1);                                             \
    _Pragma("unroll")                                                          \
    for (int kt = 0; kt < 4; ++kt)                                             \
      _Pragma("unroll")                                                        \
      for (int j = 0; j < 2; ++j) {                                            \
        f32x4 t2 = zero;                                                       \
        t2 = mfma32(kc[kt][0], qf[j][0], t2);                                  \
        t2 = mfma32(kc[kt][1], qf[j][1], t2);                                  \
        st[kt][j] = t2;                                                        \
      }                                                                        \
    __builtin_amdgcn_s_setprio(0);                                             \
    if ((T) > 0) {                                                             \
      __builtin_amdgcn_s_setprio(1);                                           \
      _Pragma("unroll")                                                        \
      for (int dt = 0; dt < 4; ++dt)                                           \
        _Pragma("unroll")                                                      \
        for (int tp = 0; tp < 2; ++tp) {                                       \
          s16x8 vv = *(const s16x8*)&(LP)[4096 + tp * 2048 + dt * 512 + ln * 8]; \
          s16x4 vlo = __builtin_shufflevector(vv, vv, 0, 1, 2, 3);             \
          s16x4 vhi = __builtin_shufflevector(vv, vv, 4, 5, 6, 7);             \
          _Pragma("unroll")                                                    \
          for (int j = 0; j < 2; ++j) {                                        \
            acc[j][dt] = mfma16((PAP)[j][tp * 2], vlo, acc[j][dt]);            \
            acc[j][dt] = mfma16((PAP)[j][tp * 2 + 1], vhi, acc[j][dt]);        \
          }                                                                    \
        }                                                                      \
      __builtin_amdgcn_s_setprio(0);                                           \
    }                                                                          \
    _Pragma("unroll")                                                          \
    for (int kt = 0; kt < 4; ++kt) {                                           \
      float p00 = exp2_(st[kt][0][0]), p01 = exp2_(st[kt][0][1]);              \
      float p02 = exp2_(st[kt][0][2]), p03 = exp2_(st[kt][0][3]);              \
      float p10 = exp2_(st[kt][1][0]), p11 = exp2_(st[kt][1][1]);              \
      float p12 = exp2_(st[kt][1][2]), p13 = exp2_(st[kt][1][3]);              \
      l0 += (p00 + p01) + (p02 + p03);                                         \
      l1 += (p10 + p11) + (p12 + p13);                                         \
      (PAC)[0][kt] = pk4(p00, p01, p02, p03);                                  \
      (PAC)[1][kt] = pk4(p10, p11, p12, p13);                                  \
    }                                                                          \
    __builtin_amdgcn_s_barrier();                                              \
  }

  for (int t = 0; t < 32; t += 2) {
    ATTN_ITER(t,     L0, L2, L1, paA, paB);
    ATTN_ITER(t + 1, L1, L0, L2, paB, paA);
    const unsigned short* tmp = L2;  // rotate (L0,L1,L2) <- (L2,L0,L1)
    L2 = L1; L1 = L0; L0 = tmp;
  }
#undef ATTN_ITER

  // final PV(31): tile 31 lives in (post-rotation) L2; pa = paB
  __builtin_amdgcn_s_setprio(1);
  #pragma unroll
  for (int dt = 0; dt < 4; ++dt)
    #pragma unroll
    for (int tp = 0; tp < 2; ++tp) {
      s16x8 vv = *(const s16x8*)&L2[4096 + tp * 2048 + dt * 512 + ln * 8];
      s16x4 vlo = __builtin_shufflevector(vv, vv, 0, 1, 2, 3);
      s16x4 vhi = __builtin_shufflevector(vv, vv, 4, 5, 6, 7);
      #pragma unroll
      for (int j = 0; j < 2; ++j) {
        acc[j][dt] = mfma16(paB[j][tp * 2], vlo, acc[j][dt]);
        acc[j][dt] = mfma16(paB[j][tp * 2 + 1], vhi, acc[j][dt]);
      }
    }
  __builtin_amdgcn_s_setprio(0);

  // final l reduction across the 4 g-copies of each q-column
  l0 += __shfl_xor(l0, 16); l0 += __shfl_xor(l0, 32);
  l1 += __shfl_xor(l1, 16); l1 += __shfl_xor(l1, 32);
  float li0 = 1.f / l0, li1 = 1.f / l1;
  int b = pair >> 4, hh = pair & 15;
  #pragma unroll
  for (int e = 0; e < 4; ++e) {
    float i0 = __shfl(li0, g * 4 + e);
    float i1 = __shfl(li1, g * 4 + e);
    size_t r0 = ((size_t)(b * 2048 + q0 + g * 4 + e) * 16 + hh) * 64;
    size_t r1 = ((size_t)(b * 2048 + q0 + 16 + g * 4 + e) * 16 + hh) * 64;
    #pragma unroll
    for (int dt = 0; dt < 4; ++dt) {
      ao[r0 + dt * 16 + c] = (unsigned short)pbf(acc[0][dt][e] * i0);
      ao[r1 + dt * 16 + c] = (unsigned short)pbf(acc[1][dt][e] * i1);
    }
  }
}

// ---------------- output GEMM: ao[4096,1024] x Wo -> fp32 out ----------------
__global__ __launch_bounds__(256)
void out_gemm(const unsigned short* __restrict__ A,
              const unsigned short* __restrict__ Bt,
              const float* __restrict__ bo, float* __restrict__ out) {
  __shared__ unsigned short lds[2][6144];   // A @0..2047, B @2048..6143
  int orig = blockIdx.x;                    // 512 wgs
  int wg = (orig & 7) * 64 + (orig >> 3);
  int bm = wg >> 3, bn = wg & 7;
  int m0 = bm << 6, n0 = bn << 7;
  int tid = threadIdx.x;
  int w = tid >> 6, ln = tid & 63;
  int g = ln >> 4, c = ln & 15;
  int wr = w >> 1, wc = w & 1;

  const unsigned short* su[3];
  int du[3];
  #pragma unroll
  for (int i = 0; i < 3; ++i) {
    int u = 3 * w + i;
    if (u < 4) {
      su[i] = A + (size_t)(m0 + u * 16 + (ln >> 2)) * 1024 + (ln & 3) * 8;
      du[i] = u * 512;
    } else {
      int v2 = u - 4;
      su[i] = Bt + (size_t)(n0 + v2 * 16 + (ln >> 2)) * 1024 + (ln & 3) * 8;
      du[i] = 2048 + v2 * 512;
    }
  }

  f32x4 acc[2][4];
  f32x4 zero = {0.f, 0.f, 0.f, 0.f};
  #pragma unroll
  for (int m = 0; m < 2; ++m)
    #pragma unroll
    for (int n = 0; n < 4; ++n) acc[m][n] = zero;

  #pragma unroll
  for (int i = 0; i < 3; ++i) GLD16(su[i], &lds[0][du[i]]);
  __syncthreads();

  int aoff = (wr * 32 + c) * 32 + g * 8;
  int boff = 2048 + (wc * 64 + c) * 32 + g * 8;

  int cur = 0;
  for (int t = 0; t < 32; ++t) {
    if (t < 31) {
      int nb = cur ^ 1;
      #pragma unroll
      for (int i = 0; i < 3; ++i) GLD16(su[i] + (t + 1) * 32, &lds[nb][du[i]]);
    }
    s16x8 af[2], bf[4];
    #pragma unroll
    for (int m = 0; m < 2; ++m)
      af[m] = *(const s16x8*)&lds[cur][aoff + m * 512];
    #pragma unroll
    for (int n = 0; n < 4; ++n)
      bf[n] = *(const s16x8*)&lds[cur][boff + n * 512];
    #pragma unroll
    for (int m = 0; m < 2; ++m)
      #pragma unroll
      for (int n = 0; n < 4; ++n)
        acc[m][n] = mfma32(af[m], bf[n], acc[m][n]);
    __syncthreads();
    cur ^= 1;
  }

  #pragma unroll
  for (int n = 0; n < 4; ++n) {
    int cg = n0 + wc * 64 + n * 16 + c;
    float bias = bo[cg];
    #pragma unroll
    for (int m = 0; m < 2; ++m) {
      int r = m0 + wr * 32 + m * 16 + g * 4;
      out[(size_t)r * 1024 + cg] = acc[m][n][0] + bias;
      out[(size_t)(r + 1) * 1024 + cg] = acc[m][n][1] + bias;
      out[(size_t)(r + 2) * 1024 + cg] = acc[m][n][2] + bias;
      out[(size_t)(r + 3) * 1024 + cg] = acc[m][n][3] + bias;
    }
  }
}

extern "C" void kernel_launch(void* const* d_in, const int* in_sizes, int n_in,
                              void* d_out, int out_size, void* d_ws, size_t ws_size,
                              hipStream_t stream) {
  (void)in_sizes; (void)n_in; (void)out_size; (void)ws_size;
  const float* x  = (const float*)d_in[0];
  const float* Wq = (const float*)d_in[1];
  const float* bq = (const float*)d_in[2];
  const float* Wk = (const float*)d_in[3];
  const float* bk = (const float*)d_in[4];
  const float* Wv = (const float*)d_in[5];
  const float* bv = (const float*)d_in[6];
  const float* Wo = (const float*)d_in[7];
  const float* bo = (const float*)d_in[8];
  float* out = (float*)d_out;
  char* ws = (char*)d_ws;
  unsigned short* xb  = (unsigned short*)(ws);             // [4096][1024] bf16
  unsigned short* Wt  = (unsigned short*)(ws + 8388608);   // [Wq^T|Wk^T|Wv^T|Wo^T]
  unsigned short* Wot = (unsigned short*)(ws + 14680064);  // = Wt + 3*1048576
  unsigned short* qb  = (unsigned short*)(ws + 16777216);  // pre-scaled q
  unsigned short* kfb = (unsigned short*)(ws + 25165824);  // K fragment-order
  unsigned short* vfb = (unsigned short*)(ws + 33554432);  // V paired-fragment-order
  unsigned short* ao  = (unsigned short*)(ws + 41943040);  // [B,S,H,Dh] bf16

  prep<<<2048, 256, 0, stream>>>(x, Wq, Wk, Wv, Wo, xb, Wt);
  qkv_gemm<<<192, 512, 0, stream>>>(xb, Wt, bq, bk, bv, qb, kfb, vfb);
  attn_fwd<<<512, 256, 0, stream>>>(qb, kfb, vfb, ao);
  out_gemm<<<512, 256, 0, stream>>>(ao, Wot, bo, out);
}

// Round 10
// 103.808 us; speedup vs baseline: 1.1321x; 1.0126x over previous
//
#include <hip/hip_runtime.h>
#include <hip/hip_bf16.h>
#include <stdint.h>

using f32x4 = __attribute__((ext_vector_type(4))) float;
using s16x8 = __attribute__((ext_vector_type(8))) short;
using s16x4 = __attribute__((ext_vector_type(4))) short;

__device__ __forceinline__ unsigned short f2bf(float f) {
  union { float f; unsigned int u; } v; v.f = f;
  return (unsigned short)((v.u + 0x7FFFu + ((v.u >> 16) & 1u)) >> 16);
}

__device__ __forceinline__ float exp2_(float x) {
  float r;
  asm("v_exp_f32 %0, %1" : "=v"(r) : "v"(x));
  return r;
}

// pack 4 f32 -> 4 bf16 via 2x v_cvt_pk_bf16_f32
__device__ __forceinline__ s16x4 pk4(float a, float b, float c, float d) {
  union { unsigned u[2]; s16x4 v; } r;
  asm("v_cvt_pk_bf16_f32 %0, %1, %2" : "=v"(r.u[0]) : "v"(a), "v"(b));
  asm("v_cvt_pk_bf16_f32 %0, %1, %2" : "=v"(r.u[1]) : "v"(c), "v"(d));
  return r.v;
}

__device__ __forceinline__ short pbf(float f) {
  __hip_bfloat16 h = __float2bfloat16(f);
  return *(short*)&h;
}

#define GLD16(gp, lp) __builtin_amdgcn_global_load_lds( \
    (const __attribute__((address_space(1))) unsigned int*)(uintptr_t)(gp), \
    (__attribute__((address_space(3))) unsigned int*)(uintptr_t)(lp), 16, 0, 0)

__device__ __forceinline__ f32x4 mfma32(s16x8 a, s16x8 b, f32x4 c) {
  return __builtin_amdgcn_mfma_f32_16x16x32_bf16(a, b, c, 0, 0, 0);
}

#if __has_builtin(__builtin_amdgcn_mfma_f32_16x16x16bf16_1k)
__device__ __forceinline__ f32x4 mfma16(s16x4 a, s16x4 b, f32x4 c) {
  return __builtin_amdgcn_mfma_f32_16x16x16bf16_1k(a, b, c, 0, 0, 0);
}
#else
__device__ __forceinline__ f32x4 mfma16(s16x4 a, s16x4 b, f32x4 c) {
  f32x4 d;
  asm volatile("v_mfma_f32_16x16x16_bf16 %0, %1, %2, %3"
               : "=v"(d) : "v"(a), "v"(b), "v"(c));
  return d;
}
#endif

// ---------------- prep: fused x-convert + 4 weight transposes ----------------
__global__ __launch_bounds__(256)
void prep(const float* __restrict__ x,
          const float* __restrict__ Wq, const float* __restrict__ Wk,
          const float* __restrict__ Wv, const float* __restrict__ Wo,
          unsigned short* __restrict__ xb, unsigned short* __restrict__ Wt) {
  __shared__ float tile[64][65];
  int blk = blockIdx.x;
  int tid = threadIdx.x;
  if (blk < 1024) {
    const float4* xi = (const float4*)x;
    ushort4* xo = (ushort4*)xb;
    #pragma unroll
    for (int j = 0; j < 4; ++j) {
      int i = blk * 1024 + j * 256 + tid;
      float4 v = xi[i];
      ushort4 o;
      o.x = f2bf(v.x); o.y = f2bf(v.y); o.z = f2bf(v.z); o.w = f2bf(v.w);
      xo[i] = o;
    }
  } else {
    int wid = blk - 1024;
    int which = wid >> 8, t = wid & 255;
    const float* W = (which == 0) ? Wq : (which == 1) ? Wk : (which == 2) ? Wv : Wo;
    unsigned short* dst = Wt + (size_t)which * 1048576;
    int k0 = (t & 15) * 64, n0 = (t >> 4) * 64;
    int tx = tid & 63, ty = tid >> 6;
    #pragma unroll
    for (int j = 0; j < 64; j += 4)
      tile[ty + j][tx] = W[(size_t)(k0 + ty + j) * 1024 + n0 + tx];
    __syncthreads();
    #pragma unroll
    for (int j = 0; j < 64; j += 4)
      dst[(size_t)(n0 + ty + j) * 1024 + k0 + tx] = f2bf(tile[tx][ty + j]);
  }
}

// ---------------- fused QKV GEMM: 256x192 tile, 8 waves, BK=64 ---------------
// [4096,1024] x [1024,3072]. Grid 16x16 = 256 wgs = exactly 1 block/CU
// (R9's 256x256 gave 192 wgs -> 25% of CUs idle). Wave = 128x48 (acc 8x3).
// LDS 2 x 57344B dbuf: A = 4 x 64-row subtiles (8KB), B = 3 subtiles.
// Stage K-tile t+1 early (7 x global_load_lds/thread, linear dest,
// pre-swizzled global source byte^=((row&7)<<4)); swizzled ds_read_b128
// fragments; one vmcnt(0)+barrier per K-tile. Epilogue scatter unchanged.
__global__ __launch_bounds__(512, 2)
void qkv_gemm(const unsigned short* __restrict__ A,
              const unsigned short* __restrict__ Bt,
              const float* __restrict__ bq, const float* __restrict__ bk,
              const float* __restrict__ bv,
              unsigned short* __restrict__ qo, unsigned short* __restrict__ kf,
              unsigned short* __restrict__ vf) {
  __shared__ unsigned short lds2[2][28672];   // per buf: A 0..16383, B 16384..28671
  int orig = blockIdx.x;                      // 256 wgs
  int wg = (orig & 7) * 32 + (orig >> 3);
  int bm = wg >> 4, bn = wg & 15;
  int m0 = bm << 8;
  int n0 = bn * 192;
  int tid = threadIdx.x;
  int w = tid >> 6, ln = tid & 63;
  int g = ln >> 4, c = ln & 15;
  int wm = w >> 2, wn = w & 3;                // 2M x 4N waves; wave = 128x48

  // staging source: thread covers row rrs of each 64-row subtile, 16B unit
  // (tid&7), column pre-swizzled by row&7.
  int rrs = tid >> 3;
  int lcol = (((tid & 7) ^ ((tid >> 3) & 7)) << 4);
  const char* pA = (const char*)A + (size_t)(m0 + rrs) * 2048 + lcol;
  const char* pB = (const char*)Bt + (size_t)(n0 + rrs) * 2048 + lcol;
  int woff = w * 1024;                        // wave-uniform dest offset

#define QKV_STAGE(buf, kt)                                                     \
  {                                                                            \
    char* db = (char*)&lds2[buf][0];                                           \
    _Pragma("unroll")                                                          \
    for (int s = 0; s < 4; ++s)                                                \
      GLD16(pA + (size_t)s * 131072 + (kt) * 128, db + s * 8192 + woff);       \
    _Pragma("unroll")                                                          \
    for (int s = 0; s < 3; ++s)                                                \
      GLD16(pB + (size_t)s * 131072 + (kt) * 128,                              \
            db + 32768 + s * 8192 + woff);                                     \
  }

  int cs = (c & 7) << 4;                      // read-side swizzle term (bytes)
  // A fragment: row mi*16+c within wave's 128-row half (subtile mi>>2)
#define DSFA(LA, mi, kk)                                                       \
  (*(const s16x8*)&(LA)[((mi) >> 2) * 4096 + (((mi) & 3) * 16 + c) * 64 +      \
                        ((((kk) * 64 + g * 16) ^ cs) >> 1)])
  // B fragment: row wn*48+ni*16+c within 192 (subtile/row computed statically)
#define DSFB(LB, ni, kk)                                                       \
  (*(const s16x8*)&(LB)[((wn * 48 + (ni) * 16) >> 6) * 4096 +                  \
                        (((wn * 48 + (ni) * 16) & 63) + c) * 64 +              \
                        ((((kk) * 64 + g * 16) ^ cs) >> 1)])

  f32x4 acc[8][3];
  f32x4 zero = {0.f, 0.f, 0.f, 0.f};
  #pragma unroll
  for (int mi = 0; mi < 8; ++mi)
    #pragma unroll
    for (int ni = 0; ni < 3; ++ni) acc[mi][ni] = zero;

  QKV_STAGE(0, 0);
  asm volatile("s_waitcnt vmcnt(0)" ::: "memory");
  __builtin_amdgcn_s_barrier();

  for (int kt = 0; kt < 16; ++kt) {
    int bsel = kt & 1;
    const unsigned short* LA = &lds2[bsel][wm * 8192];
    const unsigned short* LB = &lds2[bsel][16384];
    if (kt < 15) QKV_STAGE(bsel ^ 1, kt + 1);

    s16x8 bfr[3][2];
    #pragma unroll
    for (int ni = 0; ni < 3; ++ni) {
      bfr[ni][0] = DSFB(LB, ni, 0);
      bfr[ni][1] = DSFB(LB, ni, 1);
    }
    s16x8 a[4][2];
    // phase 1: mi 0-3
    #pragma unroll
    for (int mi = 0; mi < 4; ++mi) {
      a[mi][0] = DSFA(LA, mi, 0);
      a[mi][1] = DSFA(LA, mi, 1);
    }
    __builtin_amdgcn_s_setprio(1);
    #pragma unroll
    for (int mi = 0; mi < 4; ++mi)
      #pragma unroll
      for (int ni = 0; ni < 3; ++ni) {
        acc[mi][ni] = mfma32(a[mi][0], bfr[ni][0], acc[mi][ni]);
        acc[mi][ni] = mfma32(a[mi][1], bfr[ni][1], acc[mi][ni]);
      }
    __builtin_amdgcn_s_setprio(0);
    // phase 2: mi 4-7
    #pragma unroll
    for (int mi = 0; mi < 4; ++mi) {
      a[mi][0] = DSFA(LA, mi + 4, 0);
      a[mi][1] = DSFA(LA, mi + 4, 1);
    }
    __builtin_amdgcn_s_setprio(1);
    #pragma unroll
    for (int mi = 0; mi < 4; ++mi)
      #pragma unroll
      for (int ni = 0; ni < 3; ++ni) {
        acc[mi + 4][ni] = mfma32(a[mi][0], bfr[ni][0], acc[mi + 4][ni]);
        acc[mi + 4][ni] = mfma32(a[mi][1], bfr[ni][1], acc[mi + 4][ni]);
      }
    __builtin_amdgcn_s_setprio(0);

    asm volatile("s_waitcnt vmcnt(0)" ::: "memory");
    __builtin_amdgcn_s_barrier();
  }
#undef QKV_STAGE
#undef DSFA
#undef DSFB

  // epilogue: identical scatter math; wave = 128x48 output
  #pragma unroll
  for (int ni = 0; ni < 3; ++ni) {
    int cg = n0 + wn * 48 + ni * 16 + c;    // 0..3071
    int p = cg >> 10;                        // 0=q 1=k 2=v
    int d = cg & 1023;
    int hh = d >> 6, dh = d & 63;
    const float* bp = (p == 0) ? bq : (p == 1) ? bk : bv;
    float bias = bp[d];
    #pragma unroll
    for (int mi = 0; mi < 8; ++mi) {
      int r = m0 + wm * 128 + mi * 16 + g * 4;  // rows r..r+3 (e=0..3)
      int b2 = r >> 11, s = r & 2047;
      size_t pv = (size_t)((b2 << 4) + hh);
      if (p == 2) {
        int T = s >> 4;
        int Tp = T >> 1, par = T & 1;
        int dtp = dh >> 4;
        ushort4 pk;
        pk.x = f2bf(acc[mi][ni][0] + bias);
        pk.y = f2bf(acc[mi][ni][1] + bias);
        pk.z = f2bf(acc[mi][ni][2] + bias);
        pk.w = f2bf(acc[mi][ni][3] + bias);
        *(ushort4*)&vf[pv * 131072 +
                       (size_t)(((Tp * 4 + dtp) * 64 + g * 16 + c) * 8 + par * 4)] = pk;
      } else if (p == 1) {
        int T = s >> 4;
        int h2 = dh >> 5, gp = (dh >> 3) & 3, j = dh & 7;
        unsigned short* kd = kf + pv * 131072 + T * 1024 + h2 * 512 +
                             (gp * 16 + (s & 15)) * 8 + j;
        kd[0]  = f2bf(acc[mi][ni][0] + bias);
        kd[8]  = f2bf(acc[mi][ni][1] + bias);
        kd[16] = f2bf(acc[mi][ni][2] + bias);
        kd[24] = f2bf(acc[mi][ni][3] + bias);
      } else {
        const float sc = 0.180336880111120f;  // 1/8 * log2(e)
        size_t base = (pv * 2048 + s) * 64 + dh;
        qo[base]       = f2bf((acc[mi][ni][0] + bias) * sc);
        qo[base + 64]  = f2bf((acc[mi][ni][1] + bias) * sc);
        qo[base + 128] = f2bf((acc[mi][ni][2] + bias) * sc);
        qo[base + 192] = f2bf((acc[mi][ni][3] + bias) * sc);
      }
    }
  }
}

// ---------------- flash attention (tri-buffer, cross-iter PV pipeline) -------
__global__ __launch_bounds__(256, 2)
void attn_fwd(const unsigned short* __restrict__ q,
              const unsigned short* __restrict__ kfb,
              const unsigned short* __restrict__ vfb,
              unsigned short* __restrict__ ao) {
  __shared__ unsigned short ldsKV[3][8192];  // per buffer: K 0..4095, V 4096..8191
  int orig = blockIdx.x;                    // 512 wgs
  int wg = (orig & 7) * 64 + (orig >> 3);   // XCD-contiguous
  int pair = wg >> 4, qt = wg & 15;         // 16 blocks (128 q-rows) per pair
  int tid = threadIdx.x;
  int w = tid >> 6, ln = tid & 63;
  int g = ln >> 4, c = ln & 15;
  int q0 = qt * 128 + w * 32;
  const unsigned short* qp = q + (size_t)pair * 131072;
  const char* kbase = (const char*)(kfb + (size_t)pair * 131072);
  const char* vbase = (const char*)(vfb + (size_t)pair * 131072);

  // staging: waves 0,1 -> K halves, waves 2,3 -> V halves; 4KB each
  const char* ssrc = ((w < 2) ? kbase : vbase) + (w & 1) * 4096;
  int dsto = (w >= 2 ? 8192 : 0) + (w & 1) * 4096;  // bytes within one buffer

  s16x8 qf[2][2];
  #pragma unroll
  for (int j = 0; j < 2; ++j)
    #pragma unroll
    for (int h = 0; h < 2; ++h)
      qf[j][h] = *(const s16x8*)&qp[(q0 + j * 16 + c) * 64 + h * 32 + g * 8];

  f32x4 acc[2][4];
  f32x4 zero = {0.f, 0.f, 0.f, 0.f};
  #pragma unroll
  for (int j = 0; j < 2; ++j)
    #pragma unroll
    for (int dt = 0; dt < 4; ++dt) acc[j][dt] = zero;
  float l0 = 0.f, l1 = 0.f;

  // prologue: stage tile 0 into buffer 0
  #pragma unroll
  for (int j = 0; j < 4; ++j)
    GLD16(ssrc + j * 1024 + ln * 16, (char*)&ldsKV[0][0] + dsto + j * 1024);

  const unsigned short* L0 = ldsKV[0];
  const unsigned short* L1 = ldsKV[1];
  const unsigned short* L2 = ldsKV[2];
  s16x4 paA[2][4], paB[2][4];

#define ATTN_ITER(T, LC, LP, LN, PAC, PAP)                                     \
  {                                                                            \
    if ((T) < 31) {                                                            \
      const char* s2 = ssrc + ((T) + 1) * 8192;                                \
      char* d2 = (char*)(LN) + dsto;                                           \
      _Pragma("unroll")                                                        \
      for (int j = 0; j < 4; ++j)                                              \
        GLD16(s2 + j * 1024 + ln * 16, d2 + j * 1024);                         \
      asm volatile("s_waitcnt vmcnt(4)" ::: "memory");                         \
    } else {                                                                   \
      asm volatile("s_waitcnt vmcnt(0)" ::: "memory");                         \
    }                                                                          \
    __builtin_amdgcn_s_barrier();                                              \
    s16x8 kc[4][2];                                                            \
    _Pragma("unroll")                                                          \
    for (int kt = 0; kt < 4; ++kt) {                                           \
      kc[kt][0] = *(const s16x8*)&(LC)[kt * 1024 + ln * 8];                    \
      kc[kt][1] = *(const s16x8*)&(LC)[kt * 1024 + 512 + ln * 8];              \
    }                                                                          \
    f32x4 st[4][2];                                                            \
    __builtin_amdgcn_s_setprio(1);                                             \
    _Pragma("unroll")                                                          \
    for (int kt = 0; kt < 4; ++kt)                                             \
      _Pragma("unroll")                                                        \
      for (int j = 0; j < 2; ++j) {                                            \
        f32x4 t2 = zero;                                                       \
        t2 = mfma32(kc[kt][0], qf[j][0], t2);                                  \
        t2 = mfma32(kc[kt][1], qf[j][1], t2);                                  \
        st[kt][j] = t2;                                                        \
      }                                                                        \
    __builtin_amdgcn_s_setprio(0);                                             \
    if ((T) > 0) {                                                             \
      __builtin_amdgcn_s_setprio(1);                                           \
      _Pragma("unroll")                                                        \
      for (int dt = 0; dt < 4; ++dt)                                           \
        _Pragma("unroll")                                                      \
        for (int tp = 0; tp < 2; ++tp) {                                       \
          s16x8 vv = *(const s16x8*)&(LP)[4096 + tp * 2048 + dt * 512 + ln * 8]; \
          s16x4 vlo = __builtin_shufflevector(vv, vv, 0, 1, 2, 3);             \
          s16x4 vhi = __builtin_shufflevector(vv, vv, 4, 5, 6, 7);             \
          _Pragma("unroll")                                                    \
          for (int j = 0; j < 2; ++j) {                                        \
            acc[j][dt] = mfma16((PAP)[j][tp * 2], vlo, acc[j][dt]);            \
            acc[j][dt] = mfma16((PAP)[j][tp * 2 + 1], vhi, acc[j][dt]);        \
          }                                                                    \
        }                                                                      \
      __builtin_amdgcn_s_setprio(0);                                           \
    }                                                                          \
    _Pragma("unroll")                                                          \
    for (int kt = 0; kt < 4; ++kt) {                                           \
      float p00 = exp2_(st[kt][0][0]), p01 = exp2_(st[kt][0][1]);              \
      float p02 = exp2_(st[kt][0][2]), p03 = exp2_(st[kt][0][3]);              \
      float p10 = exp2_(st[kt][1][0]), p11 = exp2_(st[kt][1][1]);              \
      float p12 = exp2_(st[kt][1][2]), p13 = exp2_(st[kt][1][3]);              \
      l0 += (p00 + p01) + (p02 + p03);                                         \
      l1 += (p10 + p11) + (p12 + p13);                                         \
      (PAC)[0][kt] = pk4(p00, p01, p02, p03);                                  \
      (PAC)[1][kt] = pk4(p10, p11, p12, p13);                                  \
    }                                                                          \
    __builtin_amdgcn_s_barrier();                                              \
  }

  for (int t = 0; t < 32; t += 2) {
    ATTN_ITER(t,     L0, L2, L1, paA, paB);
    ATTN_ITER(t + 1, L1, L0, L2, paB, paA);
    const unsigned short* tmp = L2;  // rotate (L0,L1,L2) <- (L2,L0,L1)
    L2 = L1; L1 = L0; L0 = tmp;
  }
#undef ATTN_ITER

  // final PV(31): tile 31 lives in (post-rotation) L2; pa = paB
  __builtin_amdgcn_s_setprio(1);
  #pragma unroll
  for (int dt = 0; dt < 4; ++dt)
    #pragma unroll
    for (int tp = 0; tp < 2; ++tp) {
      s16x8 vv = *(const s16x8*)&L2[4096 + tp * 2048 + dt * 512 + ln * 8];
      s16x4 vlo = __builtin_shufflevector(vv, vv, 0, 1, 2, 3);
      s16x4 vhi = __builtin_shufflevector(vv, vv, 4, 5, 6, 7);
      #pragma unroll
      for (int j = 0; j < 2; ++j) {
        acc[j][dt] = mfma16(paB[j][tp * 2], vlo, acc[j][dt]);
        acc[j][dt] = mfma16(paB[j][tp * 2 + 1], vhi, acc[j][dt]);
      }
    }
  __builtin_amdgcn_s_setprio(0);

  // final l reduction across the 4 g-copies of each q-column
  l0 += __shfl_xor(l0, 16); l0 += __shfl_xor(l0, 32);
  l1 += __shfl_xor(l1, 16); l1 += __shfl_xor(l1, 32);
  float li0 = 1.f / l0, li1 = 1.f / l1;
  int b = pair >> 4, hh = pair & 15;
  #pragma unroll
  for (int e = 0; e < 4; ++e) {
    float i0 = __shfl(li0, g * 4 + e);
    float i1 = __shfl(li1, g * 4 + e);
    size_t r0 = ((size_t)(b * 2048 + q0 + g * 4 + e) * 16 + hh) * 64;
    size_t r1 = ((size_t)(b * 2048 + q0 + 16 + g * 4 + e) * 16 + hh) * 64;
    #pragma unroll
    for (int dt = 0; dt < 4; ++dt) {
      ao[r0 + dt * 16 + c] = (unsigned short)pbf(acc[0][dt][e] * i0);
      ao[r1 + dt * 16 + c] = (unsigned short)pbf(acc[1][dt][e] * i1);
    }
  }
}

// ---------------- output GEMM: ao[4096,1024] x Wo -> fp32 out ----------------
__global__ __launch_bounds__(256)
void out_gemm(const unsigned short* __restrict__ A,
              const unsigned short* __restrict__ Bt,
              const float* __restrict__ bo, float* __restrict__ out) {
  __shared__ unsigned short lds[2][6144];   // A @0..2047, B @2048..6143
  int orig = blockIdx.x;                    // 512 wgs
  int wg = (orig & 7) * 64 + (orig >> 3);
  int bm = wg >> 3, bn = wg & 7;
  int m0 = bm << 6, n0 = bn << 7;
  int tid = threadIdx.x;
  int w = tid >> 6, ln = tid & 63;
  int g = ln >> 4, c = ln & 15;
  int wr = w >> 1, wc = w & 1;

  const unsigned short* su[3];
  int du[3];
  #pragma unroll
  for (int i = 0; i < 3; ++i) {
    int u = 3 * w + i;
    if (u < 4) {
      su[i] = A + (size_t)(m0 + u * 16 + (ln >> 2)) * 1024 + (ln & 3) * 8;
      du[i] = u * 512;
    } else {
      int v2 = u - 4;
      su[i] = Bt + (size_t)(n0 + v2 * 16 + (ln >> 2)) * 1024 + (ln & 3) * 8;
      du[i] = 2048 + v2 * 512;
    }
  }

  f32x4 acc[2][4];
  f32x4 zero = {0.f, 0.f, 0.f, 0.f};
  #pragma unroll
  for (int m = 0; m < 2; ++m)
    #pragma unroll
    for (int n = 0; n < 4; ++n) acc[m][n] = zero;

  #pragma unroll
  for (int i = 0; i < 3; ++i) GLD16(su[i], &lds[0][du[i]]);
  __syncthreads();

  int aoff = (wr * 32 + c) * 32 + g * 8;
  int boff = 2048 + (wc * 64 + c) * 32 + g * 8;

  int cur = 0;
  for (int t = 0; t < 32; ++t) {
    if (t < 31) {
      int nb = cur ^ 1;
      #pragma unroll
      for (int i = 0; i < 3; ++i) GLD16(su[i] + (t + 1) * 32, &lds[nb][du[i]]);
    }
    s16x8 af[2], bf[4];
    #pragma unroll
    for (int m = 0; m < 2; ++m)
      af[m] = *(const s16x8*)&lds[cur][aoff + m * 512];
    #pragma unroll
    for (int n = 0; n < 4; ++n)
      bf[n] = *(const s16x8*)&lds[cur][boff + n * 512];
    #pragma unroll
    for (int m = 0; m < 2; ++m)
      #pragma unroll
      for (int n = 0; n < 4; ++n)
        acc[m][n] = mfma32(af[m], bf[n], acc[m][n]);
    __syncthreads();
    cur ^= 1;
  }

  #pragma unroll
  for (int n = 0; n < 4; ++n) {
    int cg = n0 + wc * 64 + n * 16 + c;
    float bias = bo[cg];
    #pragma unroll
    for (int m = 0; m < 2; ++m) {
      int r = m0 + wr * 32 + m * 16 + g * 4;
      out[(size_t)r * 1024 + cg] = acc[m][n][0] + bias;
      out[(size_t)(r + 1) * 1024 + cg] = acc[m][n][1] + bias;
      out[(size_t)(r + 2) * 1024 + cg] = acc[m][n][2] + bias;
      out[(size_t)(r + 3) * 1024 + cg] = acc[m][n][3] + bias;
    }
  }
}

extern "C" void kernel_launch(void* const* d_in, const int* in_sizes, int n_in,
                              void* d_out, int out_size, void* d_ws, size_t ws_size,
                              hipStream_t stream) {
  (void)in_sizes; (void)n_in; (void)out_size; (void)ws_size;
  const float* x  = (const float*)d_in[0];
  const float* Wq = (const float*)d_in[1];
  const float* bq = (const float*)d_in[2];
  const float* Wk = (const float*)d_in[3];
  const float* bk = (const float*)d_in[4];
  const float* Wv = (const float*)d_in[5];
  const float* bv = (const float*)d_in[6];
  const float* Wo = (const float*)d_in[7];
  const float* bo = (const float*)d_in[8];
  float* out = (float*)d_out;
  char* ws = (char*)d_ws;
  unsigned short* xb  = (unsigned short*)(ws);             // [4096][1024] bf16
  unsigned short* Wt  = (unsigned short*)(ws + 8388608);   // [Wq^T|Wk^T|Wv^T|Wo^T]
  unsigned short* Wot = (unsigned short*)(ws + 14680064);  // = Wt + 3*1048576
  unsigned short* qb  = (unsigned short*)(ws + 16777216);  // pre-scaled q
  unsigned short* kfb = (unsigned short*)(ws + 25165824);  // K fragment-order
  unsigned short* vfb = (unsigned short*)(ws + 33554432);  // V paired-fragment-order
  unsigned short* ao  = (unsigned short*)(ws + 41943040);  // [B,S,H,Dh] bf16

  prep<<<2048, 256, 0, stream>>>(x, Wq, Wk, Wv, Wo, xb, Wt);
  qkv_gemm<<<256, 512, 0, stream>>>(xb, Wt, bq, bk, bv, qb, kfb, vfb);
  attn_fwd<<<512, 256, 0, stream>>>(qb, kfb, vfb, ao);
  out_gemm<<<512, 256, 0, stream>>>(ao, Wot, bo, out);
}